// Round 7
// baseline (412.997 us; speedup 1.0000x reference)
//
#include <hip/hip_runtime.h>

#define N_NODES 50000
#define N_EDGES 600000
#define DH 128
#define BN_EPS 1e-5f
#define SCAN_BLOCKS ((N_NODES + 255) / 256)   // 196

typedef __attribute__((ext_vector_type(8))) short bf16x8;
typedef __attribute__((ext_vector_type(4))) float f32x4;

// round-to-nearest-even fp32 -> bf16 (bit trick, sign-safe)
__device__ inline unsigned short f2bf(float x) {
  unsigned u = __float_as_uint(x);
  return (unsigned short)((u + 0x7FFFu + ((u >> 16) & 1u)) >> 16);
}
__device__ inline float bf2f(unsigned short h) {
  return __uint_as_float(((unsigned)h) << 16);
}

// async global->LDS, 16 B per lane: lane i's data lands at lds_base + i*16.
__device__ inline void gl_lds16(const unsigned short* g, unsigned short* l) {
  __builtin_amdgcn_global_load_lds(
      (const __attribute__((address_space(1))) unsigned int*)g,
      (__attribute__((address_space(3))) unsigned int*)l, 16, 0, 0);
}

// ---------------------------------------------------------------------------
// Fused weight pre-split + edge-degree count (block-range fusion).
// Column-slot permutation: output col n placed so the epilogue lane's 4
// c-values are CONTIGUOUS output columns (colbase = ch*64 + coln*4 + c):
//   slot ct = (n>>6)*4 + (n&3), slot coln = (n>>2)&15
// k-mapping: plane[((kstep32*8 + ctile)*64 + lane)*8 + j],
// k = kstep32*32 + (lane>>4)*8 + j. W split hi/lo (Wh+Wl == W to 2^-17).
// ---------------------------------------------------------------------------
__global__ __launch_bounds__(256) void convert_W5_count(
    const float* __restrict__ hW, const float* __restrict__ g1,
    const float* __restrict__ l1, const float* __restrict__ g2,
    const float* __restrict__ l2,
    unsigned short* __restrict__ hH, unsigned short* __restrict__ hL,
    unsigned short* __restrict__ g1H, unsigned short* __restrict__ g1L,
    unsigned short* __restrict__ l1H, unsigned short* __restrict__ l1L,
    unsigned short* __restrict__ g2H, unsigned short* __restrict__ g2L,
    unsigned short* __restrict__ l2H, unsigned short* __restrict__ l2L,
    const int* __restrict__ eidx, int* __restrict__ cnt) {
  int b = blockIdx.x;
  if (b >= 512) {
    int e = (b - 512) * 256 + threadIdx.x;
    if (e < N_EDGES) atomicAdd(&cnt[eidx[N_EDGES + e]], 1);
    return;
  }
  const float* W;
  unsigned short *hi, *lo;
  int idx;
  if (b < 256) {
    W = hW; hi = hH; lo = hL;
    idx = b * 256 + threadIdx.x;
  } else {
    int w = (b - 256) >> 6;
    idx = ((b - 256) & 63) * 256 + threadIdx.x;
    W = (w == 0) ? g1 : (w == 1) ? l1 : (w == 2) ? g2 : l2;
    hi = (w == 0) ? g1H : (w == 1) ? l1H : (w == 2) ? g2H : l2H;
    lo = (w == 0) ? g1L : (w == 1) ? l1L : (w == 2) ? g2L : l2L;
  }
  int k = idx >> 7;
  int n = idx & 127;
  float x = W[idx];
  unsigned short h = f2bf(x);
  unsigned short l = f2bf(x - bf2f(h));
  int kstep = k >> 5;
  int ctile = ((n >> 6) << 2) | (n & 3);
  int cs = (n >> 2) & 15;
  int lane = ((k >> 3) & 3) * 16 + cs;
  int j = k & 7;
  size_t off = ((size_t)(kstep * 8 + ctile) * 64 + lane) * 8 + j;
  hi[off] = h;
  lo[off] = l;
}

// ---------------------------------------------------------------------------
// Head GEMM (K=512), REGISTER-A PIPELINE (R6 retry; crash was a missing
// early-clobber in the load asm - "=v" let the output alias the 64-bit
// address pair, first load clobbered the address for the second).
// The R0-R5 plateau (60-71 us, occupancy-invariant) came from A transiting
// LDS: every kstep's barrier drained the A HBM load. Now: A fragments load
// DIRECTLY to registers via single-instruction asm volatile
// global_load_dwordx4 with "=&v" outputs (compiler can't sink them - R3
// lesson; early-clobber - R6 lesson), depth-2 prefetch. The raw s_barrier +
// counted vmcnt(2) protects only B (L2, issued 1 kstep ahead, double
// buffer) and always leaves the 2 in-flight A loads outstanding.
// Wave = (rh = wave&1: 16-row frag, ch = wave>>1: 64-col half); lane l holds
// A[row=m0+rh*16+(l&15)][ks*32+(l>>4)*8..+8] - same elements/rounding as the
// LDS path, so numerics are bit-identical. BM=32, grid 1563.
// LDS = 32 KB (B double-buffer only) -> 5 blocks/CU capacity.
// ---------------------------------------------------------------------------
__global__ __launch_bounds__(256) void gemm_head(const float* __restrict__ A,
                                                 const unsigned short* __restrict__ Bh,
                                                 const unsigned short* __restrict__ Bl,
                                                 const float* __restrict__ bias,
                                                 float* __restrict__ C,
                                                 unsigned short* __restrict__ xb_out,
                                                 int M) {
  constexpr int K = 512;
  constexpr int KSTEPS = K / 32;   // 16
  __shared__ __align__(16) unsigned short Bhs[2][4096];    // 16 KB
  __shared__ __align__(16) unsigned short Bls[2][4096];    // 16 KB

  const int tid = threadIdx.x;
  const int wave = tid >> 6;
  const int lane = tid & 63;
  const int m0 = blockIdx.x * 32;

  const int rh = wave & 1;   // 16-row frag
  const int ch = wave >> 1;  // 64-col half

  // per-lane A fragment address (row-clamped; epilogue guards true rows)
  int arow = m0 + rh * 16 + (lane & 15);
  if (arow >= M) arow = M - 1;
  const float* aptr = A + (size_t)arow * K + (lane >> 4) * 8;

  auto issueB = [&](int ks, int buf) {
    const unsigned short* sh = Bh + (size_t)ks * 4096 + wave * 1024;
    const unsigned short* sl = Bl + (size_t)ks * 4096 + wave * 1024;
    gl_lds16(sh + lane * 8, &Bhs[buf][wave * 1024]);
    gl_lds16(sh + 512 + lane * 8, &Bhs[buf][wave * 1024 + 512]);
    gl_lds16(sl + lane * 8, &Bls[buf][wave * 1024]);
    gl_lds16(sl + 512 + lane * 8, &Bls[buf][wave * 1024 + 512]);
  };

  // single-instruction A-load asm: "=&v" early-clobber so the destination
  // can never alias the address pair (R6 crash fix).
  auto loadA = [&](f32x4& lo4, f32x4& hi4, const float* ap) {
    asm volatile("global_load_dwordx4 %0, %1, off"
                 : "=&v"(lo4) : "v"(ap) : "memory");
    asm volatile("global_load_dwordx4 %0, %1, off offset:16"
                 : "=&v"(hi4) : "v"(ap) : "memory");
  };

  f32x4 acc[4];
#pragma unroll
  for (int c = 0; c < 4; ++c) acc[c] = (f32x4){0.f, 0.f, 0.f, 0.f};

  // rotating A prefetch slots (ks % 3); 8 fp32 per slot
  f32x4 alo[3], ahi[3];

  // ---- prologue: A(0), B(0), A(1).  Queue: [A0(2), B0(4), A1(2)] ----
  loadA(alo[0], ahi[0], aptr);
  issueB(0, 0);
  loadA(alo[1], ahi[1], aptr + 32);

#pragma unroll
  for (int ks = 0; ks < KSTEPS; ++ks) {
    const int cur = ks & 1;
    const int s = ks % 3;
    // wait: complete A(ks)+B(ks), preserve A(ks+1) in flight. Tie A(ks)
    // regs through the asm so the cvt below can't hoist above the wait.
    if (ks < KSTEPS - 1)
      asm volatile("s_waitcnt vmcnt(2)"
                   : "+v"(alo[s]), "+v"(ahi[s]) :: "memory");
    else
      asm volatile("s_waitcnt vmcnt(0)"
                   : "+v"(alo[s]), "+v"(ahi[s]) :: "memory");
    __builtin_amdgcn_s_barrier();           // buf[cur] ready; prev reads done
    __builtin_amdgcn_sched_barrier(0);      // pin ds_reads below the barrier

    if (ks + 1 < KSTEPS) issueB(ks + 1, cur ^ 1);
    if (ks + 2 < KSTEPS) {
      const int s2 = (ks + 2) % 3;
      loadA(alo[s2], ahi[s2], aptr + (ks + 2) * 32);
    }

    // ---- convert A(ks) in registers ----
    bf16x8 a0;
    a0[0] = (short)f2bf(alo[s][0]); a0[1] = (short)f2bf(alo[s][1]);
    a0[2] = (short)f2bf(alo[s][2]); a0[3] = (short)f2bf(alo[s][3]);
    a0[4] = (short)f2bf(ahi[s][0]); a0[5] = (short)f2bf(ahi[s][1]);
    a0[6] = (short)f2bf(ahi[s][2]); a0[7] = (short)f2bf(ahi[s][3]);

    // ---- compute: 4 c-tiles x (hi+lo) = 8 MFMA / wave ----
#pragma unroll
    for (int c = 0; c < 4; ++c) {
      int ct = ch * 4 + c;
      bf16x8 bh = *(const bf16x8*)&Bhs[cur][(ct * 64 + lane) * 8];
      bf16x8 bl = *(const bf16x8*)&Bls[cur][(ct * 64 + lane) * 8];
      acc[c] = __builtin_amdgcn_mfma_f32_16x16x32_bf16(a0, bh, acc[c], 0, 0, 0);
      acc[c] = __builtin_amdgcn_mfma_f32_16x16x32_bf16(a0, bl, acc[c], 0, 0, 0);
    }
  }

  // ---- epilogue: slot c holds output col colbase+c (slot permutation) ----
  const int coln = lane & 15;
  const int rown = (lane >> 4) * 4;
  const int colbase = ch * 64 + coln * 4;
  const float4 bv = *(const float4*)(bias + colbase);
#pragma unroll
  for (int reg = 0; reg < 4; ++reg) {
    int row = m0 + rh * 16 + rown + reg;
    if (row < M) {
      float4 v;
      v.x = fmaxf(acc[0][reg] + bv.x, 0.f);
      v.y = fmaxf(acc[1][reg] + bv.y, 0.f);
      v.z = fmaxf(acc[2][reg] + bv.z, 0.f);
      v.w = fmaxf(acc[3][reg] + bv.w, 0.f);
      *(float4*)&C[(size_t)row * DH + colbase] = v;
      ushort4 hb;
      hb.x = f2bf(v.x); hb.y = f2bf(v.y); hb.z = f2bf(v.z); hb.w = f2bf(v.w);
      *(ushort4*)&xb_out[(size_t)row * DH + colbase] = hb;
    }
  }
}

// ---------------------------------------------------------------------------
// Fused GIN MLP pair (proven R2/R4 form, BM=64, grid 782) + coalesced
// epilogue with optional fused bf16 mirror (xb_out != nullptr, layer 1 only).
// Stage 1: A = yb (bf16), B = W1 planes -> h = relu(acc+b1) -> LDS Hb.
// Stage 2: A-frags ds_read from Hb, B = W2 planes.
// LDS: 5 + 16 + 17.4 = 38.4 KB.
// ---------------------------------------------------------------------------
__global__ __launch_bounds__(256) void gemm_gin(
    const unsigned short* __restrict__ yb,
    const unsigned short* __restrict__ B1h, const unsigned short* __restrict__ B1l,
    const float* __restrict__ b1,
    const unsigned short* __restrict__ B2h, const unsigned short* __restrict__ B2l,
    const float* __restrict__ b2, float* __restrict__ X,
    unsigned short* __restrict__ xb_out, int M) {
  constexpr int K = 128;
  constexpr int KSTEPS = K / 32;
  constexpr int ASTR = 40;
  constexpr int HSTR = 136;  // 128 + 8 pad
  __shared__ __align__(16) unsigned short Ah[64 * ASTR];   // 5 KB
  __shared__ __align__(16) unsigned short Bhs[4096];       // 8 KB
  __shared__ __align__(16) unsigned short Bls[4096];       // 8 KB
  __shared__ __align__(16) unsigned short Hb[64 * HSTR];   // 17.4 KB

  const int tid = threadIdx.x;
  const int wave = tid >> 6;
  const int lane = tid & 63;
  const int m0 = blockIdx.x * 64;

  const int s_row = tid >> 2;
  const int s_oct = tid & 3;
  const int g_row = m0 + s_row;
  const int g_rowc = (g_row < M) ? g_row : (M - 1);
  const unsigned short* ab = yb + (size_t)g_rowc * K + s_oct * 8;

  const int rgrp = wave & 1;
  const int ch = wave >> 1;
  const int coln = lane & 15;
  const int rown = (lane >> 4) * 4;
  const int colbase = ch * 64 + coln * 4;

  auto issueB = [&](const unsigned short* Bh, const unsigned short* Bl, int ks) {
    const unsigned short* sh = Bh + (size_t)ks * 4096 + wave * 1024;
    const unsigned short* sl = Bl + (size_t)ks * 4096 + wave * 1024;
    gl_lds16(sh + lane * 8, &Bhs[wave * 1024]);
    gl_lds16(sh + 512 + lane * 8, &Bhs[wave * 1024 + 512]);
    gl_lds16(sl + lane * 8, &Bls[wave * 1024]);
    gl_lds16(sl + 512 + lane * 8, &Bls[wave * 1024 + 512]);
  };

  f32x4 acc[2][4];
#pragma unroll
  for (int r = 0; r < 2; ++r)
#pragma unroll
    for (int c = 0; c < 4; ++c) acc[r][c] = (f32x4){0.f, 0.f, 0.f, 0.f};

  // ================= stage 1: h = relu(y @ W1 + b1) =================
  for (int ks = 0; ks < KSTEPS; ++ks) {
    *(uint4*)&Ah[s_row * ASTR + s_oct * 8] = *(const uint4*)(ab + ks * 32);
    issueB(B1h, B1l, ks);
    __syncthreads();
    bf16x8 a0 = *(const bf16x8*)&Ah[(rgrp * 32 + (lane & 15)) * ASTR + (lane >> 4) * 8];
    bf16x8 a1 = *(const bf16x8*)&Ah[(rgrp * 32 + 16 + (lane & 15)) * ASTR + (lane >> 4) * 8];
#pragma unroll
    for (int c = 0; c < 4; ++c) {
      int ct = ch * 4 + c;
      bf16x8 bh = *(const bf16x8*)&Bhs[(ct * 64 + lane) * 8];
      bf16x8 bl = *(const bf16x8*)&Bls[(ct * 64 + lane) * 8];
      acc[0][c] = __builtin_amdgcn_mfma_f32_16x16x32_bf16(a0, bh, acc[0][c], 0, 0, 0);
      acc[0][c] = __builtin_amdgcn_mfma_f32_16x16x32_bf16(a0, bl, acc[0][c], 0, 0, 0);
      acc[1][c] = __builtin_amdgcn_mfma_f32_16x16x32_bf16(a1, bh, acc[1][c], 0, 0, 0);
      acc[1][c] = __builtin_amdgcn_mfma_f32_16x16x32_bf16(a1, bl, acc[1][c], 0, 0, 0);
    }
    __syncthreads();
  }

  // ---- h -> LDS bf16: slot c holds hidden col colbase+c ----
  {
    const float4 bv = *(const float4*)(b1 + colbase);
#pragma unroll
    for (int r = 0; r < 2; ++r) {
#pragma unroll
      for (int reg = 0; reg < 4; ++reg) {
        int lrow = rgrp * 32 + r * 16 + rown + reg;
        ushort4 hb;
        hb.x = f2bf(fmaxf(acc[r][0][reg] + bv.x, 0.f));
        hb.y = f2bf(fmaxf(acc[r][1][reg] + bv.y, 0.f));
        hb.z = f2bf(fmaxf(acc[r][2][reg] + bv.z, 0.f));
        hb.w = f2bf(fmaxf(acc[r][3][reg] + bv.w, 0.f));
        *(ushort4*)&Hb[lrow * HSTR + colbase] = hb;
      }
    }
#pragma unroll
    for (int r = 0; r < 2; ++r)
#pragma unroll
      for (int c = 0; c < 4; ++c) acc[r][c] = (f32x4){0.f, 0.f, 0.f, 0.f};
  }

  // ================= stage 2: X = h @ W2 + b2 =================
  for (int ks = 0; ks < KSTEPS; ++ks) {
    issueB(B2h, B2l, ks);
    __syncthreads();  // first iter: also publishes Hb to all waves
    bf16x8 a0 = *(const bf16x8*)&Hb[(rgrp * 32 + (lane & 15)) * HSTR + ks * 32 + (lane >> 4) * 8];
    bf16x8 a1 = *(const bf16x8*)&Hb[(rgrp * 32 + 16 + (lane & 15)) * HSTR + ks * 32 + (lane >> 4) * 8];
#pragma unroll
    for (int c = 0; c < 4; ++c) {
      int ct = ch * 4 + c;
      bf16x8 bh = *(const bf16x8*)&Bhs[(ct * 64 + lane) * 8];
      bf16x8 bl = *(const bf16x8*)&Bls[(ct * 64 + lane) * 8];
      acc[0][c] = __builtin_amdgcn_mfma_f32_16x16x32_bf16(a0, bh, acc[0][c], 0, 0, 0);
      acc[0][c] = __builtin_amdgcn_mfma_f32_16x16x32_bf16(a0, bl, acc[0][c], 0, 0, 0);
      acc[1][c] = __builtin_amdgcn_mfma_f32_16x16x32_bf16(a1, bh, acc[1][c], 0, 0, 0);
      acc[1][c] = __builtin_amdgcn_mfma_f32_16x16x32_bf16(a1, bl, acc[1][c], 0, 0, 0);
    }
    __syncthreads();
  }

  // ---- epilogue: X = acc + b2 (no relu), optional fused bf16 mirror ----
  {
    const float4 bv = *(const float4*)(b2 + colbase);
#pragma unroll
    for (int r = 0; r < 2; ++r) {
#pragma unroll
      for (int reg = 0; reg < 4; ++reg) {
        int row = m0 + rgrp * 32 + r * 16 + rown + reg;
        if (row < M) {
          float4 v;
          v.x = acc[r][0][reg] + bv.x;
          v.y = acc[r][1][reg] + bv.y;
          v.z = acc[r][2][reg] + bv.z;
          v.w = acc[r][3][reg] + bv.w;
          *(float4*)&X[(size_t)row * DH + colbase] = v;
          if (xb_out) {
            ushort4 hb;
            hb.x = f2bf(v.x); hb.y = f2bf(v.y); hb.z = f2bf(v.z); hb.w = f2bf(v.w);
            *(ushort4*)&xb_out[(size_t)row * DH + colbase] = hb;
          }
        }
      }
    }
  }
}

// ---------------------------------------------------------------------------
// CSR build: exclusive scan (3 kernels) -> cursor fill. (count fused above.)
// ---------------------------------------------------------------------------
__global__ __launch_bounds__(256) void scan_block(const int* __restrict__ cnt,
                                                  int* __restrict__ rs,
                                                  int* __restrict__ partials) {
  int t = threadIdx.x;
  int i = blockIdx.x * 256 + t;
  int v = (i < N_NODES) ? cnt[i] : 0;
  __shared__ int s[256];
  s[t] = v;
  __syncthreads();
#pragma unroll
  for (int off = 1; off < 256; off <<= 1) {
    int add = (t >= off) ? s[t - off] : 0;
    __syncthreads();
    s[t] += add;
    __syncthreads();
  }
  if (i < N_NODES) rs[i] = s[t] - v;
  if (t == 255) partials[blockIdx.x] = s[255];
}

__global__ __launch_bounds__(256) void scan_partials(int* __restrict__ partials) {
  int t = threadIdx.x;
  int v = (t < SCAN_BLOCKS) ? partials[t] : 0;
  __shared__ int s[256];
  s[t] = v;
  __syncthreads();
#pragma unroll
  for (int off = 1; off < 256; off <<= 1) {
    int add = (t >= off) ? s[t - off] : 0;
    __syncthreads();
    s[t] += add;
    __syncthreads();
  }
  if (t < SCAN_BLOCKS) partials[t] = s[t] - v;
}

__global__ __launch_bounds__(256) void add_offsets(int* __restrict__ rs,
                                                   const int* __restrict__ partials) {
  int i = blockIdx.x * 256 + threadIdx.x;
  if (i < N_NODES) rs[i] += partials[blockIdx.x];
  if (i == 0) rs[N_NODES] = N_EDGES;
}

__global__ __launch_bounds__(256) void fill_csr(const int* __restrict__ eidx,
                                                const int* __restrict__ rs,
                                                int* __restrict__ cursor,
                                                int* __restrict__ esrc) {
  int e = blockIdx.x * 256 + threadIdx.x;
  if (e >= N_EDGES) return;
  int d = eidx[N_EDGES + e];
  int p = atomicAdd(&cursor[d], 1);
  esrc[rs[d] + p] = eidx[e];
}

// ---------------------------------------------------------------------------
// Aggregation gather (bf16 neighbors): yb[i] = bf16(x[i] + sum_j xb[src_j]).
// Wave per node; lane handles dims (2*lane, 2*lane+1) via one uint load/edge.
// Unrolled 8-wide for deeper MLP (mean degree = 12).
// ---------------------------------------------------------------------------
__global__ __launch_bounds__(256) void gin_aggregate_bf16(
    const unsigned short* __restrict__ xb, const float* __restrict__ x,
    const int* __restrict__ rs, const int* __restrict__ esrc,
    unsigned* __restrict__ yb) {
  int node = blockIdx.x * 4 + (threadIdx.x >> 6);
  int lane = threadIdx.x & 63;
  if (node >= N_NODES) return;
  float2 acc = ((const float2*)x)[(size_t)node * 64 + lane];
  const unsigned* xb2 = (const unsigned*)xb;  // 2 bf16 per uint
  int beg = rs[node];
  int end = rs[node + 1];
  int j = beg;
  for (; j + 8 <= end; j += 8) {
    int s0 = esrc[j + 0];
    int s1 = esrc[j + 1];
    int s2 = esrc[j + 2];
    int s3 = esrc[j + 3];
    int s4 = esrc[j + 4];
    int s5 = esrc[j + 5];
    int s6 = esrc[j + 6];
    int s7 = esrc[j + 7];
    unsigned v0 = xb2[(size_t)s0 * 64 + lane];
    unsigned v1 = xb2[(size_t)s1 * 64 + lane];
    unsigned v2 = xb2[(size_t)s2 * 64 + lane];
    unsigned v3 = xb2[(size_t)s3 * 64 + lane];
    unsigned v4 = xb2[(size_t)s4 * 64 + lane];
    unsigned v5 = xb2[(size_t)s5 * 64 + lane];
    unsigned v6 = xb2[(size_t)s6 * 64 + lane];
    unsigned v7 = xb2[(size_t)s7 * 64 + lane];
    acc.x += ((__uint_as_float(v0 << 16) + __uint_as_float(v1 << 16)) +
              (__uint_as_float(v2 << 16) + __uint_as_float(v3 << 16))) +
             ((__uint_as_float(v4 << 16) + __uint_as_float(v5 << 16)) +
              (__uint_as_float(v6 << 16) + __uint_as_float(v7 << 16)));
    acc.y += ((__uint_as_float(v0 & 0xFFFF0000u) + __uint_as_float(v1 & 0xFFFF0000u)) +
              (__uint_as_float(v2 & 0xFFFF0000u) + __uint_as_float(v3 & 0xFFFF0000u))) +
             ((__uint_as_float(v4 & 0xFFFF0000u) + __uint_as_float(v5 & 0xFFFF0000u)) +
              (__uint_as_float(v6 & 0xFFFF0000u) + __uint_as_float(v7 & 0xFFFF0000u)));
  }
  for (; j + 4 <= end; j += 4) {
    int s0 = esrc[j + 0];
    int s1 = esrc[j + 1];
    int s2 = esrc[j + 2];
    int s3 = esrc[j + 3];
    unsigned v0 = xb2[(size_t)s0 * 64 + lane];
    unsigned v1 = xb2[(size_t)s1 * 64 + lane];
    unsigned v2 = xb2[(size_t)s2 * 64 + lane];
    unsigned v3 = xb2[(size_t)s3 * 64 + lane];
    acc.x += (__uint_as_float(v0 << 16) + __uint_as_float(v1 << 16)) +
             (__uint_as_float(v2 << 16) + __uint_as_float(v3 << 16));
    acc.y += (__uint_as_float(v0 & 0xFFFF0000u) + __uint_as_float(v1 & 0xFFFF0000u)) +
             (__uint_as_float(v2 & 0xFFFF0000u) + __uint_as_float(v3 & 0xFFFF0000u));
  }
  for (; j < end; ++j) {
    unsigned v = xb2[(size_t)esrc[j] * 64 + lane];
    acc.x += __uint_as_float(v << 16);
    acc.y += __uint_as_float(v & 0xFFFF0000u);
  }
  yb[(size_t)node * 64 + lane] =
      (unsigned)f2bf(acc.x) | ((unsigned)f2bf(acc.y) << 16);
}

// ---------------------------------------------------------------------------
// Tail: z[i] = dot(x[i,:], tail_W) + tail_b, plus BN batch-stat partials.
// ---------------------------------------------------------------------------
__global__ __launch_bounds__(256) void tail_bn1(const float* __restrict__ x,
                                                const float* __restrict__ tw,
                                                const float* __restrict__ tb,
                                                float* __restrict__ z,
                                                float* __restrict__ red) {
  const int lane = threadIdx.x & 31;
  const int grp = threadIdx.x >> 5;
  float4 w = *(const float4*)(tw + lane * 4);
  float accS = 0.f, accQ = 0.f;
  for (int node = blockIdx.x * 8 + grp; node < N_NODES; node += gridDim.x * 8) {
    float4 v = *(const float4*)(x + (size_t)node * DH + lane * 4);
    float p = v.x * w.x + v.y * w.y + v.z * w.z + v.w * w.w;
#pragma unroll
    for (int m = 16; m; m >>= 1) p += __shfl_xor(p, m, 32);
    if (lane == 0) {
      float zv = p + tb[0];
      z[node] = zv;
      accS += zv;
      accQ += zv * zv;
    }
  }
  __shared__ float sS[256];
  __shared__ float sQ[256];
  sS[threadIdx.x] = accS;
  sQ[threadIdx.x] = accQ;
  __syncthreads();
  for (int s = 128; s; s >>= 1) {
    if (threadIdx.x < s) {
      sS[threadIdx.x] += sS[threadIdx.x + s];
      sQ[threadIdx.x] += sQ[threadIdx.x + s];
    }
    __syncthreads();
  }
  if (threadIdx.x == 0) {
    atomicAdd(&red[0], sS[0]);
    atomicAdd(&red[1], sQ[0]);
  }
}

__global__ __launch_bounds__(256) void bn2(const float* __restrict__ z,
                                           const float* __restrict__ red,
                                           const float* __restrict__ gamma,
                                           const float* __restrict__ beta,
                                           float* __restrict__ out) {
  int i = blockIdx.x * 256 + threadIdx.x;
  if (i >= N_NODES) return;
  float mu = red[0] * (1.0f / N_NODES);
  float var = red[1] * (1.0f / N_NODES) - mu * mu;
  out[i] = (z[i] - mu) * rsqrtf(var + BN_EPS) * gamma[0] + beta[0];
}

// ---------------------------------------------------------------------------
extern "C" void kernel_launch(void* const* d_in, const int* in_sizes, int n_in,
                              void* d_out, int out_size, void* d_ws, size_t ws_size,
                              hipStream_t stream) {
  const float* feature = (const float*)d_in[0];
  const int* eidx = (const int*)d_in[1];
  const float* head_W = (const float*)d_in[2];
  const float* head_b = (const float*)d_in[3];
  const float* gin_W1 = (const float*)d_in[4];
  const float* gin_b1 = (const float*)d_in[5];
  const float* lin_W1 = (const float*)d_in[6];
  const float* lin_b1 = (const float*)d_in[7];
  const float* gin_W2 = (const float*)d_in[8];
  const float* gin_b2 = (const float*)d_in[9];
  const float* lin_W2 = (const float*)d_in[10];
  const float* lin_b2 = (const float*)d_in[11];
  const float* tail_W = (const float*)d_in[12];
  const float* tail_b = (const float*)d_in[13];
  const float* bn_gamma = (const float*)d_in[14];
  const float* bn_beta = (const float*)d_in[15];

  float* X = (float*)d_ws;                       // N x 128 fp32
  float* z = X + (size_t)N_NODES * DH;           // N
  float* red = z + N_NODES;                      // 2 floats
  int* row_start = (int*)(red + 2);              // N+1
  int* cnt = row_start + (N_NODES + 1);          // N
  int* partials = cnt + N_NODES;                 // 256
  int* esrc = partials + 256;                    // E
  unsigned short* wp =
      (unsigned short*)(((uintptr_t)(esrc + N_EDGES) + 15) & ~(uintptr_t)15);
  unsigned short* hH = wp;            // head hi: 512*128
  unsigned short* hL = hH + 65536;    // head lo
  unsigned short* g1H = hL + 65536;   // 128*128 each below
  unsigned short* g1L = g1H + 16384;
  unsigned short* l1H = g1L + 16384;
  unsigned short* l1L = l1H + 16384;
  unsigned short* g2H = l1L + 16384;
  unsigned short* g2L = g2H + 16384;
  unsigned short* l2H = g2L + 16384;
  unsigned short* l2L = l2H + 16384;
  unsigned short* xb = l2L + 16384;              // bf16 mirror, N x 128
  unsigned short* yb = xb + (size_t)N_NODES * DH;  // agg out bf16, N x 128

  const int head_grid = (N_NODES + 31) / 32;     // 1563 (BM=32)
  const int gin_grid = (N_NODES + 63) / 64;      // 782 (BM=64)
  const int edge_grid = (N_EDGES + 255) / 256;   // 2344
  const int agg_grid = (N_NODES + 3) / 4;

  // ---- memsets first (count_deg is fused into the convert launch) ----
  hipMemsetAsync(cnt, 0, N_NODES * sizeof(int), stream);
  hipMemsetAsync(red, 0, 2 * sizeof(float), stream);

  // ---- weight pre-split + degree count: one fused launch ----
  convert_W5_count<<<512 + edge_grid, 256, 0, stream>>>(
      head_W, gin_W1, lin_W1, gin_W2, lin_W2, hH, hL, g1H, g1L, l1H, l1L,
      g2H, g2L, l2H, l2L, eidx, cnt);

  // ---- CSR build (once; reused by both GIN layers) ----
  scan_block<<<SCAN_BLOCKS, 256, 0, stream>>>(cnt, row_start, partials);
  scan_partials<<<1, 256, 0, stream>>>(partials);
  add_offsets<<<SCAN_BLOCKS, 256, 0, stream>>>(row_start, partials);
  hipMemsetAsync(cnt, 0, N_NODES * sizeof(int), stream);
  fill_csr<<<edge_grid, 256, 0, stream>>>(eidx, row_start, cnt, esrc);

  // ---- head: X = relu(feature @ head_W + head_b), fused bf16 mirror ----
  gemm_head<<<head_grid, 256, 0, stream>>>(feature, hH, hL, head_b, X, xb,
                                           N_NODES);

  // ---- layer 1 (fused GIN MLP pair; emits next bf16 mirror) ----
  gin_aggregate_bf16<<<agg_grid, 256, 0, stream>>>(xb, X, row_start, esrc,
                                                   (unsigned*)yb);
  gemm_gin<<<gin_grid, 256, 0, stream>>>(yb, g1H, g1L, gin_b1, l1H, l1L,
                                         lin_b1, X, xb, N_NODES);

  // ---- layer 2 (no bf16 mirror needed after) ----
  gin_aggregate_bf16<<<agg_grid, 256, 0, stream>>>(xb, X, row_start, esrc,
                                                   (unsigned*)yb);
  gemm_gin<<<gin_grid, 256, 0, stream>>>(yb, g2H, g2L, gin_b2, l2H, l2L,
                                         lin_b2, X, nullptr, N_NODES);

  // ---- tail + batchnorm ----
  tail_bn1<<<256, 256, 0, stream>>>(X, tail_W, tail_b, z, red);
  bn2<<<(N_NODES + 255) / 256, 256, 0, stream>>>(z, red, bn_gamma, bn_beta, (float*)d_out);
}

// Round 8
// 372.578 us; speedup vs baseline: 1.1085x; 1.1085x over previous
//
#include <hip/hip_runtime.h>

#define N_NODES 50000
#define N_EDGES 600000
#define DH 128
#define BN_EPS 1e-5f
#define SCAN_BLOCKS ((N_NODES + 255) / 256)   // 196
#define HEAD_GRID ((N_NODES + 63) / 64)       // 782

typedef __attribute__((ext_vector_type(8))) short bf16x8;
typedef __attribute__((ext_vector_type(4))) float f32x4;

// round-to-nearest-even fp32 -> bf16 (bit trick, sign-safe)
__device__ inline unsigned short f2bf(float x) {
  unsigned u = __float_as_uint(x);
  return (unsigned short)((u + 0x7FFFu + ((u >> 16) & 1u)) >> 16);
}
__device__ inline float bf2f(unsigned short h) {
  return __uint_as_float(((unsigned)h) << 16);
}

// async global->LDS, 16 B per lane: lane i's data lands at lds_base + i*16.
__device__ inline void gl_lds16(const unsigned short* g, unsigned short* l) {
  __builtin_amdgcn_global_load_lds(
      (const __attribute__((address_space(1))) unsigned int*)g,
      (__attribute__((address_space(3))) unsigned int*)l, 16, 0, 0);
}

// ---------------------------------------------------------------------------
// Fused weight pre-split + edge-degree count (block-range fusion).
// Column-slot permutation: output col n placed so the epilogue lane's 4
// c-values are CONTIGUOUS output columns (colbase = ch*64 + coln*4 + c):
//   slot ct = (n>>6)*4 + (n&3), slot coln = (n>>2)&15
// k-mapping: plane[((kstep32*8 + ctile)*64 + lane)*8 + j],
// k = kstep32*32 + (lane>>4)*8 + j. W split hi/lo (Wh+Wl == W to 2^-17).
// ---------------------------------------------------------------------------
__global__ __launch_bounds__(256) void convert_W5_count(
    const float* __restrict__ hW, const float* __restrict__ g1,
    const float* __restrict__ l1, const float* __restrict__ g2,
    const float* __restrict__ l2,
    unsigned short* __restrict__ hH, unsigned short* __restrict__ hL,
    unsigned short* __restrict__ g1H, unsigned short* __restrict__ g1L,
    unsigned short* __restrict__ l1H, unsigned short* __restrict__ l1L,
    unsigned short* __restrict__ g2H, unsigned short* __restrict__ g2L,
    unsigned short* __restrict__ l2H, unsigned short* __restrict__ l2L,
    const int* __restrict__ eidx, int* __restrict__ cnt) {
  int b = blockIdx.x;
  if (b >= 512) {
    int e = (b - 512) * 256 + threadIdx.x;
    if (e < N_EDGES) atomicAdd(&cnt[eidx[N_EDGES + e]], 1);
    return;
  }
  const float* W;
  unsigned short *hi, *lo;
  int idx;
  if (b < 256) {
    W = hW; hi = hH; lo = hL;
    idx = b * 256 + threadIdx.x;
  } else {
    int w = (b - 256) >> 6;
    idx = ((b - 256) & 63) * 256 + threadIdx.x;
    W = (w == 0) ? g1 : (w == 1) ? l1 : (w == 2) ? g2 : l2;
    hi = (w == 0) ? g1H : (w == 1) ? l1H : (w == 2) ? g2H : l2H;
    lo = (w == 0) ? g1L : (w == 1) ? l1L : (w == 2) ? g2L : l2L;
  }
  int k = idx >> 7;
  int n = idx & 127;
  float x = W[idx];
  unsigned short h = f2bf(x);
  unsigned short l = f2bf(x - bf2f(h));
  int kstep = k >> 5;
  int ctile = ((n >> 6) << 2) | (n & 3);
  int cs = (n >> 2) & 15;
  int lane = ((k >> 3) & 3) * 16 + cs;
  int j = k & 7;
  size_t off = ((size_t)(kstep * 8 + ctile) * 64 + lane) * 8 + j;
  hi[off] = h;
  lo[off] = l;
}

// ---------------------------------------------------------------------------
// Head GEMM (K=512) — R2 proven form (best measured: 60.5 us), with fill_csr
// block-range-fused (blocks >= HEAD_GRID scatter edges; independent work that
// overlaps the GEMM). BM=64, BK=64, 2 barriers/kstep, A staged via LDS with
// sync float4 loads, B via global_load_lds into per-substep buffers.
// Coalesced float4/ushort4 epilogue with fused bf16 mirror (column-slot
// permutation). LDS ~41 KB -> 3 blocks/CU.
// ---------------------------------------------------------------------------
__global__ __launch_bounds__(256) void gemm_head_fill(
    const float* __restrict__ A,
    const unsigned short* __restrict__ Bh, const unsigned short* __restrict__ Bl,
    const float* __restrict__ bias, float* __restrict__ C,
    unsigned short* __restrict__ xb_out, int M,
    const int* __restrict__ eidx, const int* __restrict__ rs,
    int* __restrict__ cursor, int* __restrict__ esrc) {
  constexpr int K = 512;
  constexpr int KSTEPS = K / 64;
  constexpr int ASTR = 72;  // 64 k + 8 pad (2-way bank alias = free)
  __shared__ __align__(16) unsigned short Ah[64 * ASTR];   // 9.2 KB
  __shared__ __align__(16) unsigned short Bhs[2][4096];    // 16 KB
  __shared__ __align__(16) unsigned short Bls[2][4096];    // 16 KB

  if (blockIdx.x >= HEAD_GRID) {
    // ---- fill_csr part: scatter edge sources into CSR slots ----
    int e = (blockIdx.x - HEAD_GRID) * 256 + threadIdx.x;
    if (e < N_EDGES) {
      int d = eidx[N_EDGES + e];
      int p = atomicAdd(&cursor[d], 1);
      esrc[rs[d] + p] = eidx[e];
    }
    return;
  }

  const int tid = threadIdx.x;
  const int wave = tid >> 6;
  const int lane = tid & 63;
  const int m0 = blockIdx.x * 64;

  // A staging: thread owns row tid>>2 (0..63), 16-elem group tid&3
  const int s_row = tid >> 2;
  const int s_grp = tid & 3;
  const int g_row = m0 + s_row;
  const int g_rowc = (g_row < M) ? g_row : (M - 1);
  const float* af = A + (size_t)g_rowc * K + s_grp * 16;

  const int rgrp = wave & 1;  // 32-row group
  const int ch = wave >> 1;   // 64-col half

  f32x4 acc[2][4];
#pragma unroll
  for (int r = 0; r < 2; ++r)
#pragma unroll
    for (int c = 0; c < 4; ++c) acc[r][c] = (f32x4){0.f, 0.f, 0.f, 0.f};

  for (int ks = 0; ks < KSTEPS; ++ks) {
    // ---- stage A (64 rows x 64 k fp32 -> bf16) ----
    {
      float4 f0 = *(const float4*)(af + ks * 64);
      float4 f1 = *(const float4*)(af + ks * 64 + 4);
      float4 f2 = *(const float4*)(af + ks * 64 + 8);
      float4 f3 = *(const float4*)(af + ks * 64 + 12);
      ushort4 h0, h1, h2, h3;
      h0.x = f2bf(f0.x); h0.y = f2bf(f0.y); h0.z = f2bf(f0.z); h0.w = f2bf(f0.w);
      h1.x = f2bf(f1.x); h1.y = f2bf(f1.y); h1.z = f2bf(f1.z); h1.w = f2bf(f1.w);
      h2.x = f2bf(f2.x); h2.y = f2bf(f2.y); h2.z = f2bf(f2.z); h2.w = f2bf(f2.w);
      h3.x = f2bf(f3.x); h3.y = f2bf(f3.y); h3.z = f2bf(f3.z); h3.w = f2bf(f3.w);
      int base = s_row * ASTR + s_grp * 16;
      *(ushort4*)&Ah[base + 0] = h0;
      *(ushort4*)&Ah[base + 4] = h1;
      *(ushort4*)&Ah[base + 8] = h2;
      *(ushort4*)&Ah[base + 12] = h3;
    }
    // ---- stage B: two 32-k sub-steps, 8 KB per plane each ----
#pragma unroll
    for (int s = 0; s < 2; ++s) {
      const unsigned short* sh = Bh + (size_t)(2 * ks + s) * 4096 + wave * 1024;
      const unsigned short* sl = Bl + (size_t)(2 * ks + s) * 4096 + wave * 1024;
      gl_lds16(sh + lane * 8, &Bhs[s][wave * 1024]);
      gl_lds16(sh + 512 + lane * 8, &Bhs[s][wave * 1024 + 512]);
      gl_lds16(sl + lane * 8, &Bls[s][wave * 1024]);
      gl_lds16(sl + 512 + lane * 8, &Bls[s][wave * 1024 + 512]);
    }
    __syncthreads();

    // ---- compute: 2 k-chunks x 4 c-tiles x (hi+lo) x 2 row-frags ----
#pragma unroll
    for (int s = 0; s < 2; ++s) {
      bf16x8 a0 = *(const bf16x8*)&Ah[(rgrp * 32 + (lane & 15)) * ASTR + s * 32 + (lane >> 4) * 8];
      bf16x8 a1 = *(const bf16x8*)&Ah[(rgrp * 32 + 16 + (lane & 15)) * ASTR + s * 32 + (lane >> 4) * 8];
#pragma unroll
      for (int c = 0; c < 4; ++c) {
        int ct = ch * 4 + c;
        bf16x8 bh = *(const bf16x8*)&Bhs[s][(ct * 64 + lane) * 8];
        bf16x8 bl = *(const bf16x8*)&Bls[s][(ct * 64 + lane) * 8];
        acc[0][c] = __builtin_amdgcn_mfma_f32_16x16x32_bf16(a0, bh, acc[0][c], 0, 0, 0);
        acc[0][c] = __builtin_amdgcn_mfma_f32_16x16x32_bf16(a0, bl, acc[0][c], 0, 0, 0);
        acc[1][c] = __builtin_amdgcn_mfma_f32_16x16x32_bf16(a1, bh, acc[1][c], 0, 0, 0);
        acc[1][c] = __builtin_amdgcn_mfma_f32_16x16x32_bf16(a1, bl, acc[1][c], 0, 0, 0);
      }
    }
    __syncthreads();
  }

  // ---- epilogue: slot c holds output col colbase+c (slot permutation) ----
  const int coln = lane & 15;
  const int rown = (lane >> 4) * 4;
  const int colbase = ch * 64 + coln * 4;
  const float4 bv = *(const float4*)(bias + colbase);
#pragma unroll
  for (int r = 0; r < 2; ++r) {
#pragma unroll
    for (int reg = 0; reg < 4; ++reg) {
      int row = m0 + rgrp * 32 + r * 16 + rown + reg;
      if (row < M) {
        float4 v;
        v.x = fmaxf(acc[r][0][reg] + bv.x, 0.f);
        v.y = fmaxf(acc[r][1][reg] + bv.y, 0.f);
        v.z = fmaxf(acc[r][2][reg] + bv.z, 0.f);
        v.w = fmaxf(acc[r][3][reg] + bv.w, 0.f);
        *(float4*)&C[(size_t)row * DH + colbase] = v;
        ushort4 hb;
        hb.x = f2bf(v.x); hb.y = f2bf(v.y); hb.z = f2bf(v.z); hb.w = f2bf(v.w);
        *(ushort4*)&xb_out[(size_t)row * DH + colbase] = hb;
      }
    }
  }
}

// ---------------------------------------------------------------------------
// Fused GIN MLP pair (proven R2/R4 form, BM=64, grid 782) + coalesced
// epilogue with optional fused bf16 mirror (xb_out != nullptr, layer 1 only).
// Stage 1: A = yb (bf16), B = W1 planes -> h = relu(acc+b1) -> LDS Hb.
// Stage 2: A-frags ds_read from Hb, B = W2 planes.
// LDS: 5 + 16 + 17.4 = 38.4 KB.
// ---------------------------------------------------------------------------
__global__ __launch_bounds__(256) void gemm_gin(
    const unsigned short* __restrict__ yb,
    const unsigned short* __restrict__ B1h, const unsigned short* __restrict__ B1l,
    const float* __restrict__ b1,
    const unsigned short* __restrict__ B2h, const unsigned short* __restrict__ B2l,
    const float* __restrict__ b2, float* __restrict__ X,
    unsigned short* __restrict__ xb_out, int M) {
  constexpr int K = 128;
  constexpr int KSTEPS = K / 32;
  constexpr int ASTR = 40;
  constexpr int HSTR = 136;  // 128 + 8 pad
  __shared__ __align__(16) unsigned short Ah[64 * ASTR];   // 5 KB
  __shared__ __align__(16) unsigned short Bhs[4096];       // 8 KB
  __shared__ __align__(16) unsigned short Bls[4096];       // 8 KB
  __shared__ __align__(16) unsigned short Hb[64 * HSTR];   // 17.4 KB

  const int tid = threadIdx.x;
  const int wave = tid >> 6;
  const int lane = tid & 63;
  const int m0 = blockIdx.x * 64;

  const int s_row = tid >> 2;
  const int s_oct = tid & 3;
  const int g_row = m0 + s_row;
  const int g_rowc = (g_row < M) ? g_row : (M - 1);
  const unsigned short* ab = yb + (size_t)g_rowc * K + s_oct * 8;

  const int rgrp = wave & 1;
  const int ch = wave >> 1;
  const int coln = lane & 15;
  const int rown = (lane >> 4) * 4;
  const int colbase = ch * 64 + coln * 4;

  auto issueB = [&](const unsigned short* Bh, const unsigned short* Bl, int ks) {
    const unsigned short* sh = Bh + (size_t)ks * 4096 + wave * 1024;
    const unsigned short* sl = Bl + (size_t)ks * 4096 + wave * 1024;
    gl_lds16(sh + lane * 8, &Bhs[wave * 1024]);
    gl_lds16(sh + 512 + lane * 8, &Bhs[wave * 1024 + 512]);
    gl_lds16(sl + lane * 8, &Bls[wave * 1024]);
    gl_lds16(sl + 512 + lane * 8, &Bls[wave * 1024 + 512]);
  };

  f32x4 acc[2][4];
#pragma unroll
  for (int r = 0; r < 2; ++r)
#pragma unroll
    for (int c = 0; c < 4; ++c) acc[r][c] = (f32x4){0.f, 0.f, 0.f, 0.f};

  // ================= stage 1: h = relu(y @ W1 + b1) =================
  for (int ks = 0; ks < KSTEPS; ++ks) {
    *(uint4*)&Ah[s_row * ASTR + s_oct * 8] = *(const uint4*)(ab + ks * 32);
    issueB(B1h, B1l, ks);
    __syncthreads();
    bf16x8 a0 = *(const bf16x8*)&Ah[(rgrp * 32 + (lane & 15)) * ASTR + (lane >> 4) * 8];
    bf16x8 a1 = *(const bf16x8*)&Ah[(rgrp * 32 + 16 + (lane & 15)) * ASTR + (lane >> 4) * 8];
#pragma unroll
    for (int c = 0; c < 4; ++c) {
      int ct = ch * 4 + c;
      bf16x8 bh = *(const bf16x8*)&Bhs[(ct * 64 + lane) * 8];
      bf16x8 bl = *(const bf16x8*)&Bls[(ct * 64 + lane) * 8];
      acc[0][c] = __builtin_amdgcn_mfma_f32_16x16x32_bf16(a0, bh, acc[0][c], 0, 0, 0);
      acc[0][c] = __builtin_amdgcn_mfma_f32_16x16x32_bf16(a0, bl, acc[0][c], 0, 0, 0);
      acc[1][c] = __builtin_amdgcn_mfma_f32_16x16x32_bf16(a1, bh, acc[1][c], 0, 0, 0);
      acc[1][c] = __builtin_amdgcn_mfma_f32_16x16x32_bf16(a1, bl, acc[1][c], 0, 0, 0);
    }
    __syncthreads();
  }

  // ---- h -> LDS bf16: slot c holds hidden col colbase+c ----
  {
    const float4 bv = *(const float4*)(b1 + colbase);
#pragma unroll
    for (int r = 0; r < 2; ++r) {
#pragma unroll
      for (int reg = 0; reg < 4; ++reg) {
        int lrow = rgrp * 32 + r * 16 + rown + reg;
        ushort4 hb;
        hb.x = f2bf(fmaxf(acc[r][0][reg] + bv.x, 0.f));
        hb.y = f2bf(fmaxf(acc[r][1][reg] + bv.y, 0.f));
        hb.z = f2bf(fmaxf(acc[r][2][reg] + bv.z, 0.f));
        hb.w = f2bf(fmaxf(acc[r][3][reg] + bv.w, 0.f));
        *(ushort4*)&Hb[lrow * HSTR + colbase] = hb;
      }
    }
#pragma unroll
    for (int r = 0; r < 2; ++r)
#pragma unroll
      for (int c = 0; c < 4; ++c) acc[r][c] = (f32x4){0.f, 0.f, 0.f, 0.f};
  }

  // ================= stage 2: X = h @ W2 + b2 =================
  for (int ks = 0; ks < KSTEPS; ++ks) {
    issueB(B2h, B2l, ks);
    __syncthreads();  // first iter: also publishes Hb to all waves
    bf16x8 a0 = *(const bf16x8*)&Hb[(rgrp * 32 + (lane & 15)) * HSTR + ks * 32 + (lane >> 4) * 8];
    bf16x8 a1 = *(const bf16x8*)&Hb[(rgrp * 32 + 16 + (lane & 15)) * HSTR + ks * 32 + (lane >> 4) * 8];
#pragma unroll
    for (int c = 0; c < 4; ++c) {
      int ct = ch * 4 + c;
      bf16x8 bh = *(const bf16x8*)&Bhs[(ct * 64 + lane) * 8];
      bf16x8 bl = *(const bf16x8*)&Bls[(ct * 64 + lane) * 8];
      acc[0][c] = __builtin_amdgcn_mfma_f32_16x16x32_bf16(a0, bh, acc[0][c], 0, 0, 0);
      acc[0][c] = __builtin_amdgcn_mfma_f32_16x16x32_bf16(a0, bl, acc[0][c], 0, 0, 0);
      acc[1][c] = __builtin_amdgcn_mfma_f32_16x16x32_bf16(a1, bh, acc[1][c], 0, 0, 0);
      acc[1][c] = __builtin_amdgcn_mfma_f32_16x16x32_bf16(a1, bl, acc[1][c], 0, 0, 0);
    }
    __syncthreads();
  }

  // ---- epilogue: X = acc + b2 (no relu), optional fused bf16 mirror ----
  {
    const float4 bv = *(const float4*)(b2 + colbase);
#pragma unroll
    for (int r = 0; r < 2; ++r) {
#pragma unroll
      for (int reg = 0; reg < 4; ++reg) {
        int row = m0 + rgrp * 32 + r * 16 + rown + reg;
        if (row < M) {
          float4 v;
          v.x = acc[r][0][reg] + bv.x;
          v.y = acc[r][1][reg] + bv.y;
          v.z = acc[r][2][reg] + bv.z;
          v.w = acc[r][3][reg] + bv.w;
          *(float4*)&X[(size_t)row * DH + colbase] = v;
          if (xb_out) {
            ushort4 hb;
            hb.x = f2bf(v.x); hb.y = f2bf(v.y); hb.z = f2bf(v.z); hb.w = f2bf(v.w);
            *(ushort4*)&xb_out[(size_t)row * DH + colbase] = hb;
          }
        }
      }
    }
  }
}

// ---------------------------------------------------------------------------
// CSR build: exclusive scan over PADDED degrees (pad to multiple of 4 so the
// aggregate's index loads are aligned int4 and its edge loop has no tails).
// Pad slots point at dummy node N_NODES whose xb row is zeroed (+0.0 terms,
// numerically exact).
// ---------------------------------------------------------------------------
__global__ __launch_bounds__(256) void scan_block(const int* __restrict__ cnt,
                                                  int* __restrict__ rs,
                                                  int* __restrict__ partials) {
  int t = threadIdx.x;
  int i = blockIdx.x * 256 + t;
  int v = (i < N_NODES) ? ((cnt[i] + 3) & ~3) : 0;   // padded degree
  __shared__ int s[256];
  s[t] = v;
  __syncthreads();
#pragma unroll
  for (int off = 1; off < 256; off <<= 1) {
    int add = (t >= off) ? s[t - off] : 0;
    __syncthreads();
    s[t] += add;
    __syncthreads();
  }
  if (i < N_NODES) rs[i] = s[t] - v;
  if (t == 255) partials[blockIdx.x] = s[255];
}

__global__ __launch_bounds__(256) void scan_partials(int* __restrict__ partials,
                                                     float* __restrict__ red) {
  int t = threadIdx.x;
  if (t == 0) { red[0] = 0.f; red[1] = 0.f; }   // BN partial reset (free ride)
  int v = (t < SCAN_BLOCKS) ? partials[t] : 0;
  __shared__ int s[256];
  s[t] = v;
  __syncthreads();
#pragma unroll
  for (int off = 1; off < 256; off <<= 1) {
    int add = (t >= off) ? s[t - off] : 0;
    __syncthreads();
    s[t] += add;
    __syncthreads();
  }
  if (t < SCAN_BLOCKS) partials[t] = s[t] - v;
}

__global__ __launch_bounds__(256) void add_offsets(int* __restrict__ rs,
                                                   const int* __restrict__ partials,
                                                   const int* __restrict__ cnt) {
  int i = blockIdx.x * 256 + threadIdx.x;
  if (i < N_NODES) {
    int v = rs[i] + partials[blockIdx.x];
    rs[i] = v;
    if (i == N_NODES - 1) rs[N_NODES] = v + ((cnt[i] + 3) & ~3);
  }
}

// pad slots -> dummy node; also zeroes cnt for the fill cursor (saves memset)
__global__ __launch_bounds__(256) void pad_fill(const int* __restrict__ rs,
                                                int* __restrict__ cnt,
                                                int* __restrict__ esrc) {
  int i = blockIdx.x * 256 + threadIdx.x;
  if (i >= N_NODES) return;
  int d = cnt[i];
  cnt[i] = 0;
  int b = rs[i] + d;
  int e = rs[i + 1];
  for (int k = b; k < e; ++k) esrc[k] = N_NODES;
}

// ---------------------------------------------------------------------------
// Aggregation gather (bf16 neighbors): yb[i] = bf16(x[i] + sum_j xb[src_j]).
// Wave per node; lane handles dims (2*lane, 2*lane+1) via one uint load/edge.
// Edge lists padded to x4 with the zero-row dummy: aligned int4 index loads,
// no scalar tails, 8-deep gather unroll (mean padded degree ~14).
// ---------------------------------------------------------------------------
__global__ __launch_bounds__(256) void gin_aggregate_bf16(
    const unsigned short* __restrict__ xb, const float* __restrict__ x,
    const int* __restrict__ rs, const int* __restrict__ esrc,
    unsigned* __restrict__ yb) {
  int node = blockIdx.x * 4 + (threadIdx.x >> 6);
  int lane = threadIdx.x & 63;
  if (node >= N_NODES) return;
  float2 acc = ((const float2*)x)[(size_t)node * 64 + lane];
  const unsigned* xb2 = (const unsigned*)xb;  // 2 bf16 per uint
  int beg = rs[node];
  int end = rs[node + 1];
  int j = beg;
  for (; j + 8 <= end; j += 8) {
    int4 ia = *(const int4*)&esrc[j];
    int4 ib = *(const int4*)&esrc[j + 4];
    unsigned v0 = xb2[(size_t)ia.x * 64 + lane];
    unsigned v1 = xb2[(size_t)ia.y * 64 + lane];
    unsigned v2 = xb2[(size_t)ia.z * 64 + lane];
    unsigned v3 = xb2[(size_t)ia.w * 64 + lane];
    unsigned v4 = xb2[(size_t)ib.x * 64 + lane];
    unsigned v5 = xb2[(size_t)ib.y * 64 + lane];
    unsigned v6 = xb2[(size_t)ib.z * 64 + lane];
    unsigned v7 = xb2[(size_t)ib.w * 64 + lane];
    acc.x += ((__uint_as_float(v0 << 16) + __uint_as_float(v1 << 16)) +
              (__uint_as_float(v2 << 16) + __uint_as_float(v3 << 16))) +
             ((__uint_as_float(v4 << 16) + __uint_as_float(v5 << 16)) +
              (__uint_as_float(v6 << 16) + __uint_as_float(v7 << 16)));
    acc.y += ((__uint_as_float(v0 & 0xFFFF0000u) + __uint_as_float(v1 & 0xFFFF0000u)) +
              (__uint_as_float(v2 & 0xFFFF0000u) + __uint_as_float(v3 & 0xFFFF0000u))) +
             ((__uint_as_float(v4 & 0xFFFF0000u) + __uint_as_float(v5 & 0xFFFF0000u)) +
              (__uint_as_float(v6 & 0xFFFF0000u) + __uint_as_float(v7 & 0xFFFF0000u)));
  }
  if (j < end) {  // exactly one aligned 4-batch remains
    int4 ia = *(const int4*)&esrc[j];
    unsigned v0 = xb2[(size_t)ia.x * 64 + lane];
    unsigned v1 = xb2[(size_t)ia.y * 64 + lane];
    unsigned v2 = xb2[(size_t)ia.z * 64 + lane];
    unsigned v3 = xb2[(size_t)ia.w * 64 + lane];
    acc.x += (__uint_as_float(v0 << 16) + __uint_as_float(v1 << 16)) +
             (__uint_as_float(v2 << 16) + __uint_as_float(v3 << 16));
    acc.y += (__uint_as_float(v0 & 0xFFFF0000u) + __uint_as_float(v1 & 0xFFFF0000u)) +
             (__uint_as_float(v2 & 0xFFFF0000u) + __uint_as_float(v3 & 0xFFFF0000u));
  }
  yb[(size_t)node * 64 + lane] =
      (unsigned)f2bf(acc.x) | ((unsigned)f2bf(acc.y) << 16);
}

// ---------------------------------------------------------------------------
// Tail: z[i] = dot(x[i,:], tail_W) + tail_b, plus BN batch-stat partials.
// ---------------------------------------------------------------------------
__global__ __launch_bounds__(256) void tail_bn1(const float* __restrict__ x,
                                                const float* __restrict__ tw,
                                                const float* __restrict__ tb,
                                                float* __restrict__ z,
                                                float* __restrict__ red) {
  const int lane = threadIdx.x & 31;
  const int grp = threadIdx.x >> 5;
  float4 w = *(const float4*)(tw + lane * 4);
  float accS = 0.f, accQ = 0.f;
  for (int node = blockIdx.x * 8 + grp; node < N_NODES; node += gridDim.x * 8) {
    float4 v = *(const float4*)(x + (size_t)node * DH + lane * 4);
    float p = v.x * w.x + v.y * w.y + v.z * w.z + v.w * w.w;
#pragma unroll
    for (int m = 16; m; m >>= 1) p += __shfl_xor(p, m, 32);
    if (lane == 0) {
      float zv = p + tb[0];
      z[node] = zv;
      accS += zv;
      accQ += zv * zv;
    }
  }
  __shared__ float sS[256];
  __shared__ float sQ[256];
  sS[threadIdx.x] = accS;
  sQ[threadIdx.x] = accQ;
  __syncthreads();
  for (int s = 128; s; s >>= 1) {
    if (threadIdx.x < s) {
      sS[threadIdx.x] += sS[threadIdx.x + s];
      sQ[threadIdx.x] += sQ[threadIdx.x + s];
    }
    __syncthreads();
  }
  if (threadIdx.x == 0) {
    atomicAdd(&red[0], sS[0]);
    atomicAdd(&red[1], sQ[0]);
  }
}

__global__ __launch_bounds__(256) void bn2(const float* __restrict__ z,
                                           const float* __restrict__ red,
                                           const float* __restrict__ gamma,
                                           const float* __restrict__ beta,
                                           float* __restrict__ out) {
  int i = blockIdx.x * 256 + threadIdx.x;
  if (i >= N_NODES) return;
  float mu = red[0] * (1.0f / N_NODES);
  float var = red[1] * (1.0f / N_NODES) - mu * mu;
  out[i] = (z[i] - mu) * rsqrtf(var + BN_EPS) * gamma[0] + beta[0];
}

// ---------------------------------------------------------------------------
extern "C" void kernel_launch(void* const* d_in, const int* in_sizes, int n_in,
                              void* d_out, int out_size, void* d_ws, size_t ws_size,
                              hipStream_t stream) {
  const float* feature = (const float*)d_in[0];
  const int* eidx = (const int*)d_in[1];
  const float* head_W = (const float*)d_in[2];
  const float* head_b = (const float*)d_in[3];
  const float* gin_W1 = (const float*)d_in[4];
  const float* gin_b1 = (const float*)d_in[5];
  const float* lin_W1 = (const float*)d_in[6];
  const float* lin_b1 = (const float*)d_in[7];
  const float* gin_W2 = (const float*)d_in[8];
  const float* gin_b2 = (const float*)d_in[9];
  const float* lin_W2 = (const float*)d_in[10];
  const float* lin_b2 = (const float*)d_in[11];
  const float* tail_W = (const float*)d_in[12];
  const float* tail_b = (const float*)d_in[13];
  const float* bn_gamma = (const float*)d_in[14];
  const float* bn_beta = (const float*)d_in[15];

  float* X = (float*)d_ws;                       // N x 128 fp32
  float* z = X + (size_t)N_NODES * DH;           // N
  float* red = z + N_NODES;                      // 2 floats
  int* row_start = (int*)(red + 2);              // N+1
  int* cnt = row_start + (N_NODES + 1);          // N
  int* partials = cnt + N_NODES;                 // 256
  int* esrc = (int*)(((uintptr_t)(partials + 256) + 15) & ~(uintptr_t)15);
  // padded CSR: at most E + 3*N = 750000 slots
  unsigned short* wp =
      (unsigned short*)(((uintptr_t)(esrc + 760000) + 15) & ~(uintptr_t)15);
  unsigned short* hH = wp;            // head hi: 512*128
  unsigned short* hL = hH + 65536;    // head lo
  unsigned short* g1H = hL + 65536;   // 128*128 each below
  unsigned short* g1L = g1H + 16384;
  unsigned short* l1H = g1L + 16384;
  unsigned short* l1L = l1H + 16384;
  unsigned short* g2H = l1L + 16384;
  unsigned short* g2L = g2H + 16384;
  unsigned short* l2H = g2L + 16384;
  unsigned short* l2L = l2H + 16384;
  unsigned short* xb = l2L + 16384;              // bf16 mirror, (N+1) x 128
  unsigned short* yb = xb + (size_t)(N_NODES + 1) * DH;  // agg out bf16, N x 128

  const int gin_grid = (N_NODES + 63) / 64;      // 782 (BM=64)
  const int edge_grid = (N_EDGES + 255) / 256;   // 2344
  const int agg_grid = (N_NODES + 3) / 4;

  // ---- zero degree counters + the dummy zero row of xb ----
  hipMemsetAsync(cnt, 0, N_NODES * sizeof(int), stream);
  hipMemsetAsync(xb + (size_t)N_NODES * DH, 0, DH * sizeof(unsigned short), stream);

  // ---- weight pre-split + degree count: one fused launch ----
  convert_W5_count<<<512 + edge_grid, 256, 0, stream>>>(
      head_W, gin_W1, lin_W1, gin_W2, lin_W2, hH, hL, g1H, g1L, l1H, l1L,
      g2H, g2L, l2H, l2L, eidx, cnt);

  // ---- CSR build over padded degrees ----
  scan_block<<<SCAN_BLOCKS, 256, 0, stream>>>(cnt, row_start, partials);
  scan_partials<<<1, 256, 0, stream>>>(partials, red);   // also zeroes red
  add_offsets<<<SCAN_BLOCKS, 256, 0, stream>>>(row_start, partials, cnt);
  pad_fill<<<SCAN_BLOCKS, 256, 0, stream>>>(row_start, cnt, esrc);  // also zeroes cnt

  // ---- head GEMM (fused with fill_csr: independent work overlaps) ----
  gemm_head_fill<<<HEAD_GRID + edge_grid, 256, 0, stream>>>(
      feature, hH, hL, head_b, X, xb, N_NODES, eidx, row_start, cnt, esrc);

  // ---- layer 1 (fused GIN MLP pair; emits next bf16 mirror) ----
  gin_aggregate_bf16<<<agg_grid, 256, 0, stream>>>(xb, X, row_start, esrc,
                                                   (unsigned*)yb);
  gemm_gin<<<gin_grid, 256, 0, stream>>>(yb, g1H, g1L, gin_b1, l1H, l1L,
                                         lin_b1, X, xb, N_NODES);

  // ---- layer 2 (no bf16 mirror needed after) ----
  gin_aggregate_bf16<<<agg_grid, 256, 0, stream>>>(xb, X, row_start, esrc,
                                                   (unsigned*)yb);
  gemm_gin<<<gin_grid, 256, 0, stream>>>(yb, g2H, g2L, gin_b2, l2H, l2L,
                                         lin_b2, X, nullptr, N_NODES);

  // ---- tail + batchnorm ----
  tail_bn1<<<512, 256, 0, stream>>>(X, tail_W, tail_b, z, red);
  bn2<<<(N_NODES + 255) / 256, 256, 0, stream>>>(z, red, bn_gamma, bn_beta, (float*)d_out);
}

// Round 9
// 366.653 us; speedup vs baseline: 1.1264x; 1.0162x over previous
//
#include <hip/hip_runtime.h>

#define N_NODES 50000
#define N_EDGES 600000
#define DH 128
#define BN_EPS 1e-5f
#define SCAN_BLOCKS ((N_NODES + 255) / 256)   // 196
#define HEAD_GRID ((N_NODES + 63) / 64)       // 782

typedef __attribute__((ext_vector_type(8))) short bf16x8;
typedef __attribute__((ext_vector_type(4))) float f32x4;

// round-to-nearest-even fp32 -> bf16 (bit trick, sign-safe)
__device__ inline unsigned short f2bf(float x) {
  unsigned u = __float_as_uint(x);
  return (unsigned short)((u + 0x7FFFu + ((u >> 16) & 1u)) >> 16);
}
__device__ inline float bf2f(unsigned short h) {
  return __uint_as_float(((unsigned)h) << 16);
}

// async global->LDS, 16 B per lane: lane i's data lands at lds_base + i*16.
__device__ inline void gl_lds16(const unsigned short* g, unsigned short* l) {
  __builtin_amdgcn_global_load_lds(
      (const __attribute__((address_space(1))) unsigned int*)g,
      (__attribute__((address_space(3))) unsigned int*)l, 16, 0, 0);
}

// ---------------------------------------------------------------------------
// Fused weight pre-split + edge-degree count (block-range fusion) + xb dummy
// row zero (block 0 rides along; consumed only by the much-later aggregate).
// Column-slot permutation: output col n placed so the epilogue lane's 4
// c-values are CONTIGUOUS output columns (colbase = ch*64 + coln*4 + c):
//   slot ct = (n>>6)*4 + (n&3), slot coln = (n>>2)&15
// k-mapping: plane[((kstep32*8 + ctile)*64 + lane)*8 + j],
// k = kstep32*32 + (lane>>4)*8 + j. W split hi/lo (Wh+Wl == W to 2^-17).
// ---------------------------------------------------------------------------
__global__ __launch_bounds__(256) void convert_W5_count(
    const float* __restrict__ hW, const float* __restrict__ g1,
    const float* __restrict__ l1, const float* __restrict__ g2,
    const float* __restrict__ l2,
    unsigned short* __restrict__ hH, unsigned short* __restrict__ hL,
    unsigned short* __restrict__ g1H, unsigned short* __restrict__ g1L,
    unsigned short* __restrict__ l1H, unsigned short* __restrict__ l1L,
    unsigned short* __restrict__ g2H, unsigned short* __restrict__ g2L,
    unsigned short* __restrict__ l2H, unsigned short* __restrict__ l2L,
    const int* __restrict__ eidx, int* __restrict__ cnt,
    unsigned* __restrict__ xb_dummy) {
  int b = blockIdx.x;
  if (b >= 512) {
    int e = (b - 512) * 256 + threadIdx.x;
    if (e < N_EDGES) atomicAdd(&cnt[eidx[N_EDGES + e]], 1);
    return;
  }
  if (b == 0 && threadIdx.x < 64) xb_dummy[threadIdx.x] = 0u;  // 128 bf16 zeros
  const float* W;
  unsigned short *hi, *lo;
  int idx;
  if (b < 256) {
    W = hW; hi = hH; lo = hL;
    idx = b * 256 + threadIdx.x;
  } else {
    int w = (b - 256) >> 6;
    idx = ((b - 256) & 63) * 256 + threadIdx.x;
    W = (w == 0) ? g1 : (w == 1) ? l1 : (w == 2) ? g2 : l2;
    hi = (w == 0) ? g1H : (w == 1) ? l1H : (w == 2) ? g2H : l2H;
    lo = (w == 0) ? g1L : (w == 1) ? l1L : (w == 2) ? g2L : l2L;
  }
  int k = idx >> 7;
  int n = idx & 127;
  float x = W[idx];
  unsigned short h = f2bf(x);
  unsigned short l = f2bf(x - bf2f(h));
  int kstep = k >> 5;
  int ctile = ((n >> 6) << 2) | (n & 3);
  int cs = (n >> 2) & 15;
  int lane = ((k >> 3) & 3) * 16 + cs;
  int j = k & 7;
  size_t off = ((size_t)(kstep * 8 + ctile) * 64 + lane) * 8 + j;
  hi[off] = h;
  lo[off] = l;
}

// ---------------------------------------------------------------------------
// Head GEMM (K=512) — R2 proven form, with fill_csr block-range-fused
// (blocks >= HEAD_GRID scatter edges; independent work that overlaps the
// GEMM). BM=64, BK=64, 2 barriers/kstep; coalesced float4/ushort4 epilogue
// with fused bf16 mirror (column-slot permutation). LDS ~41 KB.
// ---------------------------------------------------------------------------
__global__ __launch_bounds__(256) void gemm_head_fill(
    const float* __restrict__ A,
    const unsigned short* __restrict__ Bh, const unsigned short* __restrict__ Bl,
    const float* __restrict__ bias, float* __restrict__ C,
    unsigned short* __restrict__ xb_out, int M,
    const int* __restrict__ eidx, const int* __restrict__ rs,
    int* __restrict__ cursor, int* __restrict__ esrc) {
  constexpr int K = 512;
  constexpr int KSTEPS = K / 64;
  constexpr int ASTR = 72;  // 64 k + 8 pad (2-way bank alias = free)
  __shared__ __align__(16) unsigned short Ah[64 * ASTR];   // 9.2 KB
  __shared__ __align__(16) unsigned short Bhs[2][4096];    // 16 KB
  __shared__ __align__(16) unsigned short Bls[2][4096];    // 16 KB

  if (blockIdx.x >= HEAD_GRID) {
    // ---- fill_csr part: scatter edge sources into CSR slots ----
    int e = (blockIdx.x - HEAD_GRID) * 256 + threadIdx.x;
    if (e < N_EDGES) {
      int d = eidx[N_EDGES + e];
      int p = atomicAdd(&cursor[d], 1);
      esrc[rs[d] + p] = eidx[e];
    }
    return;
  }

  const int tid = threadIdx.x;
  const int wave = tid >> 6;
  const int lane = tid & 63;
  const int m0 = blockIdx.x * 64;

  // A staging: thread owns row tid>>2 (0..63), 16-elem group tid&3
  const int s_row = tid >> 2;
  const int s_grp = tid & 3;
  const int g_row = m0 + s_row;
  const int g_rowc = (g_row < M) ? g_row : (M - 1);
  const float* af = A + (size_t)g_rowc * K + s_grp * 16;

  const int rgrp = wave & 1;  // 32-row group
  const int ch = wave >> 1;   // 64-col half

  f32x4 acc[2][4];
#pragma unroll
  for (int r = 0; r < 2; ++r)
#pragma unroll
    for (int c = 0; c < 4; ++c) acc[r][c] = (f32x4){0.f, 0.f, 0.f, 0.f};

  for (int ks = 0; ks < KSTEPS; ++ks) {
    // ---- stage A (64 rows x 64 k fp32 -> bf16) ----
    {
      float4 f0 = *(const float4*)(af + ks * 64);
      float4 f1 = *(const float4*)(af + ks * 64 + 4);
      float4 f2 = *(const float4*)(af + ks * 64 + 8);
      float4 f3 = *(const float4*)(af + ks * 64 + 12);
      ushort4 h0, h1, h2, h3;
      h0.x = f2bf(f0.x); h0.y = f2bf(f0.y); h0.z = f2bf(f0.z); h0.w = f2bf(f0.w);
      h1.x = f2bf(f1.x); h1.y = f2bf(f1.y); h1.z = f2bf(f1.z); h1.w = f2bf(f1.w);
      h2.x = f2bf(f2.x); h2.y = f2bf(f2.y); h2.z = f2bf(f2.z); h2.w = f2bf(f2.w);
      h3.x = f2bf(f3.x); h3.y = f2bf(f3.y); h3.z = f2bf(f3.z); h3.w = f2bf(f3.w);
      int base = s_row * ASTR + s_grp * 16;
      *(ushort4*)&Ah[base + 0] = h0;
      *(ushort4*)&Ah[base + 4] = h1;
      *(ushort4*)&Ah[base + 8] = h2;
      *(ushort4*)&Ah[base + 12] = h3;
    }
    // ---- stage B: two 32-k sub-steps, 8 KB per plane each ----
#pragma unroll
    for (int s = 0; s < 2; ++s) {
      const unsigned short* sh = Bh + (size_t)(2 * ks + s) * 4096 + wave * 1024;
      const unsigned short* sl = Bl + (size_t)(2 * ks + s) * 4096 + wave * 1024;
      gl_lds16(sh + lane * 8, &Bhs[s][wave * 1024]);
      gl_lds16(sh + 512 + lane * 8, &Bhs[s][wave * 1024 + 512]);
      gl_lds16(sl + lane * 8, &Bls[s][wave * 1024]);
      gl_lds16(sl + 512 + lane * 8, &Bls[s][wave * 1024 + 512]);
    }
    __syncthreads();

    // ---- compute: 2 k-chunks x 4 c-tiles x (hi+lo) x 2 row-frags ----
#pragma unroll
    for (int s = 0; s < 2; ++s) {
      bf16x8 a0 = *(const bf16x8*)&Ah[(rgrp * 32 + (lane & 15)) * ASTR + s * 32 + (lane >> 4) * 8];
      bf16x8 a1 = *(const bf16x8*)&Ah[(rgrp * 32 + 16 + (lane & 15)) * ASTR + s * 32 + (lane >> 4) * 8];
#pragma unroll
      for (int c = 0; c < 4; ++c) {
        int ct = ch * 4 + c;
        bf16x8 bh = *(const bf16x8*)&Bhs[s][(ct * 64 + lane) * 8];
        bf16x8 bl = *(const bf16x8*)&Bls[s][(ct * 64 + lane) * 8];
        acc[0][c] = __builtin_amdgcn_mfma_f32_16x16x32_bf16(a0, bh, acc[0][c], 0, 0, 0);
        acc[0][c] = __builtin_amdgcn_mfma_f32_16x16x32_bf16(a0, bl, acc[0][c], 0, 0, 0);
        acc[1][c] = __builtin_amdgcn_mfma_f32_16x16x32_bf16(a1, bh, acc[1][c], 0, 0, 0);
        acc[1][c] = __builtin_amdgcn_mfma_f32_16x16x32_bf16(a1, bl, acc[1][c], 0, 0, 0);
      }
    }
    __syncthreads();
  }

  // ---- epilogue: slot c holds output col colbase+c (slot permutation) ----
  const int coln = lane & 15;
  const int rown = (lane >> 4) * 4;
  const int colbase = ch * 64 + coln * 4;
  const float4 bv = *(const float4*)(bias + colbase);
#pragma unroll
  for (int r = 0; r < 2; ++r) {
#pragma unroll
    for (int reg = 0; reg < 4; ++reg) {
      int row = m0 + rgrp * 32 + r * 16 + rown + reg;
      if (row < M) {
        float4 v;
        v.x = fmaxf(acc[r][0][reg] + bv.x, 0.f);
        v.y = fmaxf(acc[r][1][reg] + bv.y, 0.f);
        v.z = fmaxf(acc[r][2][reg] + bv.z, 0.f);
        v.w = fmaxf(acc[r][3][reg] + bv.w, 0.f);
        *(float4*)&C[(size_t)row * DH + colbase] = v;
        ushort4 hb;
        hb.x = f2bf(v.x); hb.y = f2bf(v.y); hb.z = f2bf(v.z); hb.w = f2bf(v.w);
        *(ushort4*)&xb_out[(size_t)row * DH + colbase] = hb;
      }
    }
  }
}

// ---------------------------------------------------------------------------
// Fused GIN MLP pair (proven R2/R4 form, BM=64, grid 782).
// Stage 1: A = yb (bf16), B = W1 planes -> h = relu(acc+b1) -> LDS Hb.
// Stage 2: A-frags ds_read from Hb, B = W2 planes.
// Epilogue modes:
//   tw == nullptr (layer 1): write X fp32 + xb bf16 mirror (coalesced).
//   tw != nullptr (layer 2): FUSED TAIL — no X/xb write at all. Each thread
//     dots its 4 cols with tail_W, stores to zpart[row][ch*16+coln] (Hb
//     reused; slots provably unique & conflict-light), wave 0 then sums each
//     row's 32 slots in fixed order -> z[row], shfl-reduces 64 rows -> 2
//     global atomicAdds of BN partials. Saves X write + tail's X re-read +
//     the tail_bn1 launch. z differs from the old path only by fp32
//     reassociation (~1e-6 << absmax budget).
// LDS: 5 + 16 + 17.4 = 38.4 KB.
// ---------------------------------------------------------------------------
__global__ __launch_bounds__(256) void gemm_gin(
    const unsigned short* __restrict__ yb,
    const unsigned short* __restrict__ B1h, const unsigned short* __restrict__ B1l,
    const float* __restrict__ b1,
    const unsigned short* __restrict__ B2h, const unsigned short* __restrict__ B2l,
    const float* __restrict__ b2, float* __restrict__ X,
    unsigned short* __restrict__ xb_out, int M,
    const float* __restrict__ tw, const float* __restrict__ tb,
    float* __restrict__ z, float* __restrict__ red) {
  constexpr int K = 128;
  constexpr int KSTEPS = K / 32;
  constexpr int ASTR = 40;
  constexpr int HSTR = 136;  // 128 + 8 pad
  __shared__ __align__(16) unsigned short Ah[64 * ASTR];   // 5 KB
  __shared__ __align__(16) unsigned short Bhs[4096];       // 8 KB
  __shared__ __align__(16) unsigned short Bls[4096];       // 8 KB
  __shared__ __align__(16) unsigned short Hb[64 * HSTR];   // 17.4 KB

  const int tid = threadIdx.x;
  const int wave = tid >> 6;
  const int lane = tid & 63;
  const int m0 = blockIdx.x * 64;

  const int s_row = tid >> 2;
  const int s_oct = tid & 3;
  const int g_row = m0 + s_row;
  const int g_rowc = (g_row < M) ? g_row : (M - 1);
  const unsigned short* ab = yb + (size_t)g_rowc * K + s_oct * 8;

  const int rgrp = wave & 1;
  const int ch = wave >> 1;
  const int coln = lane & 15;
  const int rown = (lane >> 4) * 4;
  const int colbase = ch * 64 + coln * 4;

  auto issueB = [&](const unsigned short* Bh, const unsigned short* Bl, int ks) {
    const unsigned short* sh = Bh + (size_t)ks * 4096 + wave * 1024;
    const unsigned short* sl = Bl + (size_t)ks * 4096 + wave * 1024;
    gl_lds16(sh + lane * 8, &Bhs[wave * 1024]);
    gl_lds16(sh + 512 + lane * 8, &Bhs[wave * 1024 + 512]);
    gl_lds16(sl + lane * 8, &Bls[wave * 1024]);
    gl_lds16(sl + 512 + lane * 8, &Bls[wave * 1024 + 512]);
  };

  f32x4 acc[2][4];
#pragma unroll
  for (int r = 0; r < 2; ++r)
#pragma unroll
    for (int c = 0; c < 4; ++c) acc[r][c] = (f32x4){0.f, 0.f, 0.f, 0.f};

  // ================= stage 1: h = relu(y @ W1 + b1) =================
  for (int ks = 0; ks < KSTEPS; ++ks) {
    *(uint4*)&Ah[s_row * ASTR + s_oct * 8] = *(const uint4*)(ab + ks * 32);
    issueB(B1h, B1l, ks);
    __syncthreads();
    bf16x8 a0 = *(const bf16x8*)&Ah[(rgrp * 32 + (lane & 15)) * ASTR + (lane >> 4) * 8];
    bf16x8 a1 = *(const bf16x8*)&Ah[(rgrp * 32 + 16 + (lane & 15)) * ASTR + (lane >> 4) * 8];
#pragma unroll
    for (int c = 0; c < 4; ++c) {
      int ct = ch * 4 + c;
      bf16x8 bh = *(const bf16x8*)&Bhs[(ct * 64 + lane) * 8];
      bf16x8 bl = *(const bf16x8*)&Bls[(ct * 64 + lane) * 8];
      acc[0][c] = __builtin_amdgcn_mfma_f32_16x16x32_bf16(a0, bh, acc[0][c], 0, 0, 0);
      acc[0][c] = __builtin_amdgcn_mfma_f32_16x16x32_bf16(a0, bl, acc[0][c], 0, 0, 0);
      acc[1][c] = __builtin_amdgcn_mfma_f32_16x16x32_bf16(a1, bh, acc[1][c], 0, 0, 0);
      acc[1][c] = __builtin_amdgcn_mfma_f32_16x16x32_bf16(a1, bl, acc[1][c], 0, 0, 0);
    }
    __syncthreads();
  }

  // ---- h -> LDS bf16: slot c holds hidden col colbase+c ----
  {
    const float4 bv = *(const float4*)(b1 + colbase);
#pragma unroll
    for (int r = 0; r < 2; ++r) {
#pragma unroll
      for (int reg = 0; reg < 4; ++reg) {
        int lrow = rgrp * 32 + r * 16 + rown + reg;
        ushort4 hb;
        hb.x = f2bf(fmaxf(acc[r][0][reg] + bv.x, 0.f));
        hb.y = f2bf(fmaxf(acc[r][1][reg] + bv.y, 0.f));
        hb.z = f2bf(fmaxf(acc[r][2][reg] + bv.z, 0.f));
        hb.w = f2bf(fmaxf(acc[r][3][reg] + bv.w, 0.f));
        *(ushort4*)&Hb[lrow * HSTR + colbase] = hb;
      }
    }
#pragma unroll
    for (int r = 0; r < 2; ++r)
#pragma unroll
      for (int c = 0; c < 4; ++c) acc[r][c] = (f32x4){0.f, 0.f, 0.f, 0.f};
  }

  // ================= stage 2: X = h @ W2 + b2 =================
  for (int ks = 0; ks < KSTEPS; ++ks) {
    issueB(B2h, B2l, ks);
    __syncthreads();  // first iter: also publishes Hb to all waves
    bf16x8 a0 = *(const bf16x8*)&Hb[(rgrp * 32 + (lane & 15)) * HSTR + ks * 32 + (lane >> 4) * 8];
    bf16x8 a1 = *(const bf16x8*)&Hb[(rgrp * 32 + 16 + (lane & 15)) * HSTR + ks * 32 + (lane >> 4) * 8];
#pragma unroll
    for (int c = 0; c < 4; ++c) {
      int ct = ch * 4 + c;
      bf16x8 bh = *(const bf16x8*)&Bhs[(ct * 64 + lane) * 8];
      bf16x8 bl = *(const bf16x8*)&Bls[(ct * 64 + lane) * 8];
      acc[0][c] = __builtin_amdgcn_mfma_f32_16x16x32_bf16(a0, bh, acc[0][c], 0, 0, 0);
      acc[0][c] = __builtin_amdgcn_mfma_f32_16x16x32_bf16(a0, bl, acc[0][c], 0, 0, 0);
      acc[1][c] = __builtin_amdgcn_mfma_f32_16x16x32_bf16(a1, bh, acc[1][c], 0, 0, 0);
      acc[1][c] = __builtin_amdgcn_mfma_f32_16x16x32_bf16(a1, bl, acc[1][c], 0, 0, 0);
    }
    __syncthreads();  // last iter: Hb reads complete -> safe to reuse below
  }

  const float4 bv = *(const float4*)(b2 + colbase);

  if (tw == nullptr) {
    // ---- layer-1 epilogue: X fp32 + bf16 mirror (coalesced) ----
#pragma unroll
    for (int r = 0; r < 2; ++r) {
#pragma unroll
      for (int reg = 0; reg < 4; ++reg) {
        int row = m0 + rgrp * 32 + r * 16 + rown + reg;
        if (row < M) {
          float4 v;
          v.x = acc[r][0][reg] + bv.x;
          v.y = acc[r][1][reg] + bv.y;
          v.z = acc[r][2][reg] + bv.z;
          v.w = acc[r][3][reg] + bv.w;
          *(float4*)&X[(size_t)row * DH + colbase] = v;
          ushort4 hb;
          hb.x = f2bf(v.x); hb.y = f2bf(v.y); hb.z = f2bf(v.z); hb.w = f2bf(v.w);
          *(ushort4*)&xb_out[(size_t)row * DH + colbase] = hb;
        }
      }
    }
  } else {
    // ---- layer-2 fused-tail epilogue: z + BN partials, no X/xb write ----
    float* zpart = (float*)Hb;  // 64 x 33 fp32 = 8.4 KB (fits in 17.4 KB)
    const float4 tw4 = *(const float4*)(tw + colbase);
#pragma unroll
    for (int r = 0; r < 2; ++r) {
#pragma unroll
      for (int reg = 0; reg < 4; ++reg) {
        int lrow = rgrp * 32 + r * 16 + rown + reg;
        float4 v;
        v.x = acc[r][0][reg] + bv.x;
        v.y = acc[r][1][reg] + bv.y;
        v.z = acc[r][2][reg] + bv.z;
        v.w = acc[r][3][reg] + bv.w;
        zpart[lrow * 33 + ch * 16 + coln] =
            v.x * tw4.x + v.y * tw4.y + v.z * tw4.z + v.w * tw4.w;
      }
    }
    __syncthreads();
    if (tid < 64) {
      int row = m0 + tid;
      float s = 0.f;
#pragma unroll
      for (int k = 0; k < 32; ++k) s += zpart[tid * 33 + k];
      float zv = s + tb[0];
      bool valid = row < M;
      if (valid) z[row] = zv;
      float a = valid ? zv : 0.f;
      float q = valid ? zv * zv : 0.f;
#pragma unroll
      for (int m = 32; m; m >>= 1) {
        a += __shfl_xor(a, m);
        q += __shfl_xor(q, m);
      }
      if (tid == 0) {
        atomicAdd(&red[0], a);
        atomicAdd(&red[1], q);
      }
    }
  }
}

// ---------------------------------------------------------------------------
// CSR build: exclusive scan over PADDED degrees (pad to multiple of 4 so the
// aggregate's index loads are aligned int4 and its edge loop has no tails).
// Pad slots point at dummy node N_NODES whose xb row is zeroed (+0.0 terms,
// numerically exact).
// ---------------------------------------------------------------------------
__global__ __launch_bounds__(256) void scan_block(const int* __restrict__ cnt,
                                                  int* __restrict__ rs,
                                                  int* __restrict__ partials) {
  int t = threadIdx.x;
  int i = blockIdx.x * 256 + t;
  int v = (i < N_NODES) ? ((cnt[i] + 3) & ~3) : 0;   // padded degree
  __shared__ int s[256];
  s[t] = v;
  __syncthreads();
#pragma unroll
  for (int off = 1; off < 256; off <<= 1) {
    int add = (t >= off) ? s[t - off] : 0;
    __syncthreads();
    s[t] += add;
    __syncthreads();
  }
  if (i < N_NODES) rs[i] = s[t] - v;
  if (t == 255) partials[blockIdx.x] = s[255];
}

__global__ __launch_bounds__(256) void scan_partials(int* __restrict__ partials,
                                                     float* __restrict__ red) {
  int t = threadIdx.x;
  if (t == 0) { red[0] = 0.f; red[1] = 0.f; }   // BN partial reset (free ride)
  int v = (t < SCAN_BLOCKS) ? partials[t] : 0;
  __shared__ int s[256];
  s[t] = v;
  __syncthreads();
#pragma unroll
  for (int off = 1; off < 256; off <<= 1) {
    int add = (t >= off) ? s[t - off] : 0;
    __syncthreads();
    s[t] += add;
    __syncthreads();
  }
  if (t < SCAN_BLOCKS) partials[t] = s[t] - v;
}

__global__ __launch_bounds__(256) void add_offsets(int* __restrict__ rs,
                                                   const int* __restrict__ partials,
                                                   const int* __restrict__ cnt) {
  int i = blockIdx.x * 256 + threadIdx.x;
  if (i < N_NODES) {
    int v = rs[i] + partials[blockIdx.x];
    rs[i] = v;
    if (i == N_NODES - 1) rs[N_NODES] = v + ((cnt[i] + 3) & ~3);
  }
}

// pad slots -> dummy node; also zeroes cnt for the fill cursor (saves memset)
__global__ __launch_bounds__(256) void pad_fill(const int* __restrict__ rs,
                                                int* __restrict__ cnt,
                                                int* __restrict__ esrc) {
  int i = blockIdx.x * 256 + threadIdx.x;
  if (i >= N_NODES) return;
  int d = cnt[i];
  cnt[i] = 0;
  int b = rs[i] + d;
  int e = rs[i + 1];
  for (int k = b; k < e; ++k) esrc[k] = N_NODES;
}

// ---------------------------------------------------------------------------
// Aggregation gather (bf16 neighbors): yb[i] = bf16(x[i] + sum_j xb[src_j]).
// Wave per node; lane handles dims (2*lane, 2*lane+1) via one uint load/edge.
// Edge lists padded to x4 with the zero-row dummy: aligned int4 index loads,
// no scalar tails, 8-deep gather unroll (mean padded degree ~14).
// ---------------------------------------------------------------------------
__global__ __launch_bounds__(256) void gin_aggregate_bf16(
    const unsigned short* __restrict__ xb, const float* __restrict__ x,
    const int* __restrict__ rs, const int* __restrict__ esrc,
    unsigned* __restrict__ yb) {
  int node = blockIdx.x * 4 + (threadIdx.x >> 6);
  int lane = threadIdx.x & 63;
  if (node >= N_NODES) return;
  float2 acc = ((const float2*)x)[(size_t)node * 64 + lane];
  const unsigned* xb2 = (const unsigned*)xb;  // 2 bf16 per uint
  int beg = rs[node];
  int end = rs[node + 1];
  int j = beg;
  for (; j + 8 <= end; j += 8) {
    int4 ia = *(const int4*)&esrc[j];
    int4 ib = *(const int4*)&esrc[j + 4];
    unsigned v0 = xb2[(size_t)ia.x * 64 + lane];
    unsigned v1 = xb2[(size_t)ia.y * 64 + lane];
    unsigned v2 = xb2[(size_t)ia.z * 64 + lane];
    unsigned v3 = xb2[(size_t)ia.w * 64 + lane];
    unsigned v4 = xb2[(size_t)ib.x * 64 + lane];
    unsigned v5 = xb2[(size_t)ib.y * 64 + lane];
    unsigned v6 = xb2[(size_t)ib.z * 64 + lane];
    unsigned v7 = xb2[(size_t)ib.w * 64 + lane];
    acc.x += ((__uint_as_float(v0 << 16) + __uint_as_float(v1 << 16)) +
              (__uint_as_float(v2 << 16) + __uint_as_float(v3 << 16))) +
             ((__uint_as_float(v4 << 16) + __uint_as_float(v5 << 16)) +
              (__uint_as_float(v6 << 16) + __uint_as_float(v7 << 16)));
    acc.y += ((__uint_as_float(v0 & 0xFFFF0000u) + __uint_as_float(v1 & 0xFFFF0000u)) +
              (__uint_as_float(v2 & 0xFFFF0000u) + __uint_as_float(v3 & 0xFFFF0000u))) +
             ((__uint_as_float(v4 & 0xFFFF0000u) + __uint_as_float(v5 & 0xFFFF0000u)) +
              (__uint_as_float(v6 & 0xFFFF0000u) + __uint_as_float(v7 & 0xFFFF0000u)));
  }
  if (j < end) {  // exactly one aligned 4-batch remains
    int4 ia = *(const int4*)&esrc[j];
    unsigned v0 = xb2[(size_t)ia.x * 64 + lane];
    unsigned v1 = xb2[(size_t)ia.y * 64 + lane];
    unsigned v2 = xb2[(size_t)ia.z * 64 + lane];
    unsigned v3 = xb2[(size_t)ia.w * 64 + lane];
    acc.x += (__uint_as_float(v0 << 16) + __uint_as_float(v1 << 16)) +
             (__uint_as_float(v2 << 16) + __uint_as_float(v3 << 16));
    acc.y += (__uint_as_float(v0 & 0xFFFF0000u) + __uint_as_float(v1 & 0xFFFF0000u)) +
             (__uint_as_float(v2 & 0xFFFF0000u) + __uint_as_float(v3 & 0xFFFF0000u));
  }
  yb[(size_t)node * 64 + lane] =
      (unsigned)f2bf(acc.x) | ((unsigned)f2bf(acc.y) << 16);
}

// ---------------------------------------------------------------------------
// BN apply: out = (z - mu) * rsqrt(var + eps) * gamma + beta.
// ---------------------------------------------------------------------------
__global__ __launch_bounds__(256) void bn2(const float* __restrict__ z,
                                           const float* __restrict__ red,
                                           const float* __restrict__ gamma,
                                           const float* __restrict__ beta,
                                           float* __restrict__ out) {
  int i = blockIdx.x * 256 + threadIdx.x;
  if (i >= N_NODES) return;
  float mu = red[0] * (1.0f / N_NODES);
  float var = red[1] * (1.0f / N_NODES) - mu * mu;
  out[i] = (z[i] - mu) * rsqrtf(var + BN_EPS) * gamma[0] + beta[0];
}

// ---------------------------------------------------------------------------
extern "C" void kernel_launch(void* const* d_in, const int* in_sizes, int n_in,
                              void* d_out, int out_size, void* d_ws, size_t ws_size,
                              hipStream_t stream) {
  const float* feature = (const float*)d_in[0];
  const int* eidx = (const int*)d_in[1];
  const float* head_W = (const float*)d_in[2];
  const float* head_b = (const float*)d_in[3];
  const float* gin_W1 = (const float*)d_in[4];
  const float* gin_b1 = (const float*)d_in[5];
  const float* lin_W1 = (const float*)d_in[6];
  const float* lin_b1 = (const float*)d_in[7];
  const float* gin_W2 = (const float*)d_in[8];
  const float* gin_b2 = (const float*)d_in[9];
  const float* lin_W2 = (const float*)d_in[10];
  const float* lin_b2 = (const float*)d_in[11];
  const float* tail_W = (const float*)d_in[12];
  const float* tail_b = (const float*)d_in[13];
  const float* bn_gamma = (const float*)d_in[14];
  const float* bn_beta = (const float*)d_in[15];

  float* X = (float*)d_ws;                       // N x 128 fp32
  float* z = X + (size_t)N_NODES * DH;           // N
  float* red = z + N_NODES;                      // 2 floats
  int* row_start = (int*)(red + 2);              // N+1
  int* cnt = row_start + (N_NODES + 1);          // N
  int* partials = cnt + N_NODES;                 // 256
  int* esrc = (int*)(((uintptr_t)(partials + 256) + 15) & ~(uintptr_t)15);
  // padded CSR: at most E + 3*N = 750000 slots
  unsigned short* wp =
      (unsigned short*)(((uintptr_t)(esrc + 760000) + 15) & ~(uintptr_t)15);
  unsigned short* hH = wp;            // head hi: 512*128
  unsigned short* hL = hH + 65536;    // head lo
  unsigned short* g1H = hL + 65536;   // 128*128 each below
  unsigned short* g1L = g1H + 16384;
  unsigned short* l1H = g1L + 16384;
  unsigned short* l1L = l1H + 16384;
  unsigned short* g2H = l1L + 16384;
  unsigned short* g2L = g2H + 16384;
  unsigned short* l2H = g2L + 16384;
  unsigned short* l2L = l2H + 16384;
  unsigned short* xb = l2L + 16384;              // bf16 mirror, (N+1) x 128
  unsigned short* yb = xb + (size_t)(N_NODES + 1) * DH;  // agg out bf16, N x 128

  const int gin_grid = (N_NODES + 63) / 64;      // 782 (BM=64)
  const int edge_grid = (N_EDGES + 255) / 256;   // 2344
  const int agg_grid = (N_NODES + 3) / 4;

  // ---- zero degree counters ----
  hipMemsetAsync(cnt, 0, N_NODES * sizeof(int), stream);

  // ---- weight pre-split + degree count + xb dummy zero: one launch ----
  convert_W5_count<<<512 + edge_grid, 256, 0, stream>>>(
      head_W, gin_W1, lin_W1, gin_W2, lin_W2, hH, hL, g1H, g1L, l1H, l1L,
      g2H, g2L, l2H, l2L, eidx, cnt,
      (unsigned*)(xb + (size_t)N_NODES * DH));

  // ---- CSR build over padded degrees ----
  scan_block<<<SCAN_BLOCKS, 256, 0, stream>>>(cnt, row_start, partials);
  scan_partials<<<1, 256, 0, stream>>>(partials, red);   // also zeroes red
  add_offsets<<<SCAN_BLOCKS, 256, 0, stream>>>(row_start, partials, cnt);
  pad_fill<<<SCAN_BLOCKS, 256, 0, stream>>>(row_start, cnt, esrc);  // also zeroes cnt

  // ---- head GEMM (fused with fill_csr: independent work overlaps) ----
  gemm_head_fill<<<HEAD_GRID + edge_grid, 256, 0, stream>>>(
      feature, hH, hL, head_b, X, xb, N_NODES, eidx, row_start, cnt, esrc);

  // ---- layer 1 (fused GIN MLP pair; emits X + next bf16 mirror) ----
  gin_aggregate_bf16<<<agg_grid, 256, 0, stream>>>(xb, X, row_start, esrc,
                                                   (unsigned*)yb);
  gemm_gin<<<gin_grid, 256, 0, stream>>>(yb, g1H, g1L, gin_b1, l1H, l1L,
                                         lin_b1, X, xb, N_NODES,
                                         nullptr, nullptr, nullptr, nullptr);

  // ---- layer 2 (fused tail: z + BN partials; no X/xb write) ----
  gin_aggregate_bf16<<<agg_grid, 256, 0, stream>>>(xb, X, row_start, esrc,
                                                   (unsigned*)yb);
  gemm_gin<<<gin_grid, 256, 0, stream>>>(yb, g2H, g2L, gin_b2, l2H, l2L,
                                         lin_b2, X, nullptr, N_NODES,
                                         tail_W, tail_b, z, red);

  // ---- batchnorm apply ----
  bn2<<<(N_NODES + 255) / 256, 256, 0, stream>>>(z, red, bn_gamma, bn_beta, (float*)d_out);
}

// Round 10
// 364.296 us; speedup vs baseline: 1.1337x; 1.0065x over previous
//
#include <hip/hip_runtime.h>

#define N_NODES 50000
#define N_EDGES 600000
#define DH 128
#define BN_EPS 1e-5f
#define SCAN_BLOCKS ((N_NODES + 255) / 256)   // 196
#define HEAD_GRID ((N_NODES + 63) / 64)       // 782

typedef __attribute__((ext_vector_type(8))) short bf16x8;
typedef __attribute__((ext_vector_type(4))) float f32x4;

// round-to-nearest-even fp32 -> bf16 (bit trick, sign-safe)
__device__ inline unsigned short f2bf(float x) {
  unsigned u = __float_as_uint(x);
  return (unsigned short)((u + 0x7FFFu + ((u >> 16) & 1u)) >> 16);
}
__device__ inline float bf2f(unsigned short h) {
  return __uint_as_float(((unsigned)h) << 16);
}

// async global->LDS, 16 B per lane: lane i's data lands at lds_base + i*16.
__device__ inline void gl_lds16(const unsigned short* g, unsigned short* l) {
  __builtin_amdgcn_global_load_lds(
      (const __attribute__((address_space(1))) unsigned int*)g,
      (__attribute__((address_space(3))) unsigned int*)l, 16, 0, 0);
}

// ---------------------------------------------------------------------------
// Fused weight pre-split + edge-degree count (block-range fusion) + xb dummy
// row zero (block 0 rides along; consumed only by the much-later aggregate).
// Column-slot permutation: output col n placed so the epilogue lane's 4
// c-values are CONTIGUOUS output columns (colbase = ch*64 + coln*4 + c):
//   slot ct = (n>>6)*4 + (n&3), slot coln = (n>>2)&15
// k-mapping: plane[((kstep32*8 + ctile)*64 + lane)*8 + j],
// k = kstep32*32 + (lane>>4)*8 + j. W split hi/lo (Wh+Wl == W to 2^-17).
// ---------------------------------------------------------------------------
__global__ __launch_bounds__(256) void convert_W5_count(
    const float* __restrict__ hW, const float* __restrict__ g1,
    const float* __restrict__ l1, const float* __restrict__ g2,
    const float* __restrict__ l2,
    unsigned short* __restrict__ hH, unsigned short* __restrict__ hL,
    unsigned short* __restrict__ g1H, unsigned short* __restrict__ g1L,
    unsigned short* __restrict__ l1H, unsigned short* __restrict__ l1L,
    unsigned short* __restrict__ g2H, unsigned short* __restrict__ g2L,
    unsigned short* __restrict__ l2H, unsigned short* __restrict__ l2L,
    const int* __restrict__ eidx, int* __restrict__ cnt,
    unsigned* __restrict__ xb_dummy) {
  int b = blockIdx.x;
  if (b >= 512) {
    int e = (b - 512) * 256 + threadIdx.x;
    if (e < N_EDGES) atomicAdd(&cnt[eidx[N_EDGES + e]], 1);
    return;
  }
  if (b == 0 && threadIdx.x < 64) xb_dummy[threadIdx.x] = 0u;  // 128 bf16 zeros
  const float* W;
  unsigned short *hi, *lo;
  int idx;
  if (b < 256) {
    W = hW; hi = hH; lo = hL;
    idx = b * 256 + threadIdx.x;
  } else {
    int w = (b - 256) >> 6;
    idx = ((b - 256) & 63) * 256 + threadIdx.x;
    W = (w == 0) ? g1 : (w == 1) ? l1 : (w == 2) ? g2 : l2;
    hi = (w == 0) ? g1H : (w == 1) ? l1H : (w == 2) ? g2H : l2H;
    lo = (w == 0) ? g1L : (w == 1) ? l1L : (w == 2) ? g2L : l2L;
  }
  int k = idx >> 7;
  int n = idx & 127;
  float x = W[idx];
  unsigned short h = f2bf(x);
  unsigned short l = f2bf(x - bf2f(h));
  int kstep = k >> 5;
  int ctile = ((n >> 6) << 2) | (n & 3);
  int cs = (n >> 2) & 15;
  int lane = ((k >> 3) & 3) * 16 + cs;
  int j = k & 7;
  size_t off = ((size_t)(kstep * 8 + ctile) * 64 + lane) * 8 + j;
  hi[off] = h;
  lo[off] = l;
}

// ---------------------------------------------------------------------------
// Head GEMM (K=512) — R2 proven form + fused fill_csr. NEW (R10): fp32 X is
// DROPPED pipeline-wide; the epilogue writes only the bf16 mirror (aggregate
// self-terms now read xb — the extra bf16 rounding is 1 of ~13 comparable
// error sources in the y-sum, which gets bf16-rounded anyway). Saves 102 MB
// of X traffic across head/agg1/gin1/agg2.
// ---------------------------------------------------------------------------
__global__ __launch_bounds__(256) void gemm_head_fill(
    const float* __restrict__ A,
    const unsigned short* __restrict__ Bh, const unsigned short* __restrict__ Bl,
    const float* __restrict__ bias,
    unsigned short* __restrict__ xb_out, int M,
    const int* __restrict__ eidx, const int* __restrict__ rs,
    int* __restrict__ cursor, int* __restrict__ esrc) {
  constexpr int K = 512;
  constexpr int KSTEPS = K / 64;
  constexpr int ASTR = 72;  // 64 k + 8 pad (2-way bank alias = free)
  __shared__ __align__(16) unsigned short Ah[64 * ASTR];   // 9.2 KB
  __shared__ __align__(16) unsigned short Bhs[2][4096];    // 16 KB
  __shared__ __align__(16) unsigned short Bls[2][4096];    // 16 KB

  if (blockIdx.x >= HEAD_GRID) {
    // ---- fill_csr part: scatter edge sources into CSR slots ----
    int e = (blockIdx.x - HEAD_GRID) * 256 + threadIdx.x;
    if (e < N_EDGES) {
      int d = eidx[N_EDGES + e];
      int p = atomicAdd(&cursor[d], 1);
      esrc[rs[d] + p] = eidx[e];
    }
    return;
  }

  const int tid = threadIdx.x;
  const int wave = tid >> 6;
  const int lane = tid & 63;
  const int m0 = blockIdx.x * 64;

  // A staging: thread owns row tid>>2 (0..63), 16-elem group tid&3
  const int s_row = tid >> 2;
  const int s_grp = tid & 3;
  const int g_row = m0 + s_row;
  const int g_rowc = (g_row < M) ? g_row : (M - 1);
  const float* af = A + (size_t)g_rowc * K + s_grp * 16;

  const int rgrp = wave & 1;  // 32-row group
  const int ch = wave >> 1;   // 64-col half

  f32x4 acc[2][4];
#pragma unroll
  for (int r = 0; r < 2; ++r)
#pragma unroll
    for (int c = 0; c < 4; ++c) acc[r][c] = (f32x4){0.f, 0.f, 0.f, 0.f};

  for (int ks = 0; ks < KSTEPS; ++ks) {
    // ---- stage A (64 rows x 64 k fp32 -> bf16) ----
    {
      float4 f0 = *(const float4*)(af + ks * 64);
      float4 f1 = *(const float4*)(af + ks * 64 + 4);
      float4 f2 = *(const float4*)(af + ks * 64 + 8);
      float4 f3 = *(const float4*)(af + ks * 64 + 12);
      ushort4 h0, h1, h2, h3;
      h0.x = f2bf(f0.x); h0.y = f2bf(f0.y); h0.z = f2bf(f0.z); h0.w = f2bf(f0.w);
      h1.x = f2bf(f1.x); h1.y = f2bf(f1.y); h1.z = f2bf(f1.z); h1.w = f2bf(f1.w);
      h2.x = f2bf(f2.x); h2.y = f2bf(f2.y); h2.z = f2bf(f2.z); h2.w = f2bf(f2.w);
      h3.x = f2bf(f3.x); h3.y = f2bf(f3.y); h3.z = f2bf(f3.z); h3.w = f2bf(f3.w);
      int base = s_row * ASTR + s_grp * 16;
      *(ushort4*)&Ah[base + 0] = h0;
      *(ushort4*)&Ah[base + 4] = h1;
      *(ushort4*)&Ah[base + 8] = h2;
      *(ushort4*)&Ah[base + 12] = h3;
    }
    // ---- stage B: two 32-k sub-steps, 8 KB per plane each ----
#pragma unroll
    for (int s = 0; s < 2; ++s) {
      const unsigned short* sh = Bh + (size_t)(2 * ks + s) * 4096 + wave * 1024;
      const unsigned short* sl = Bl + (size_t)(2 * ks + s) * 4096 + wave * 1024;
      gl_lds16(sh + lane * 8, &Bhs[s][wave * 1024]);
      gl_lds16(sh + 512 + lane * 8, &Bhs[s][wave * 1024 + 512]);
      gl_lds16(sl + lane * 8, &Bls[s][wave * 1024]);
      gl_lds16(sl + 512 + lane * 8, &Bls[s][wave * 1024 + 512]);
    }
    __syncthreads();

    // ---- compute: 2 k-chunks x 4 c-tiles x (hi+lo) x 2 row-frags ----
#pragma unroll
    for (int s = 0; s < 2; ++s) {
      bf16x8 a0 = *(const bf16x8*)&Ah[(rgrp * 32 + (lane & 15)) * ASTR + s * 32 + (lane >> 4) * 8];
      bf16x8 a1 = *(const bf16x8*)&Ah[(rgrp * 32 + 16 + (lane & 15)) * ASTR + s * 32 + (lane >> 4) * 8];
#pragma unroll
      for (int c = 0; c < 4; ++c) {
        int ct = ch * 4 + c;
        bf16x8 bh = *(const bf16x8*)&Bhs[s][(ct * 64 + lane) * 8];
        bf16x8 bl = *(const bf16x8*)&Bls[s][(ct * 64 + lane) * 8];
        acc[0][c] = __builtin_amdgcn_mfma_f32_16x16x32_bf16(a0, bh, acc[0][c], 0, 0, 0);
        acc[0][c] = __builtin_amdgcn_mfma_f32_16x16x32_bf16(a0, bl, acc[0][c], 0, 0, 0);
        acc[1][c] = __builtin_amdgcn_mfma_f32_16x16x32_bf16(a1, bh, acc[1][c], 0, 0, 0);
        acc[1][c] = __builtin_amdgcn_mfma_f32_16x16x32_bf16(a1, bl, acc[1][c], 0, 0, 0);
      }
    }
    __syncthreads();
  }

  // ---- epilogue: bf16 mirror only (slot c = output col colbase+c) ----
  const int coln = lane & 15;
  const int rown = (lane >> 4) * 4;
  const int colbase = ch * 64 + coln * 4;
  const float4 bv = *(const float4*)(bias + colbase);
#pragma unroll
  for (int r = 0; r < 2; ++r) {
#pragma unroll
    for (int reg = 0; reg < 4; ++reg) {
      int row = m0 + rgrp * 32 + r * 16 + rown + reg;
      if (row < M) {
        ushort4 hb;
        hb.x = f2bf(fmaxf(acc[r][0][reg] + bv.x, 0.f));
        hb.y = f2bf(fmaxf(acc[r][1][reg] + bv.y, 0.f));
        hb.z = f2bf(fmaxf(acc[r][2][reg] + bv.z, 0.f));
        hb.w = f2bf(fmaxf(acc[r][3][reg] + bv.w, 0.f));
        *(ushort4*)&xb_out[(size_t)row * DH + colbase] = hb;
      }
    }
  }
}

// ---------------------------------------------------------------------------
// Fused GIN MLP pair (proven form, BM=64, grid 782).
// Stage 1: A = yb (bf16), B = W1 planes -> h = relu(acc+b1) -> LDS Hb.
// Stage 2: A-frags ds_read from Hb, B = W2 planes.
// Epilogue modes:
//   tw == nullptr (layer 1): write xb bf16 mirror only (X dropped, R10).
//   tw != nullptr (layer 2): FUSED TAIL — z + BN partials via LDS zpart +
//     wave-0 reduction; no global feature write.
// LDS: 5 + 16 + 17.4 = 38.4 KB.
// ---------------------------------------------------------------------------
__global__ __launch_bounds__(256) void gemm_gin(
    const unsigned short* __restrict__ yb,
    const unsigned short* __restrict__ B1h, const unsigned short* __restrict__ B1l,
    const float* __restrict__ b1,
    const unsigned short* __restrict__ B2h, const unsigned short* __restrict__ B2l,
    const float* __restrict__ b2,
    unsigned short* __restrict__ xb_out, int M,
    const float* __restrict__ tw, const float* __restrict__ tb,
    float* __restrict__ z, float* __restrict__ red) {
  constexpr int K = 128;
  constexpr int KSTEPS = K / 32;
  constexpr int ASTR = 40;
  constexpr int HSTR = 136;  // 128 + 8 pad
  __shared__ __align__(16) unsigned short Ah[64 * ASTR];   // 5 KB
  __shared__ __align__(16) unsigned short Bhs[4096];       // 8 KB
  __shared__ __align__(16) unsigned short Bls[4096];       // 8 KB
  __shared__ __align__(16) unsigned short Hb[64 * HSTR];   // 17.4 KB

  const int tid = threadIdx.x;
  const int wave = tid >> 6;
  const int lane = tid & 63;
  const int m0 = blockIdx.x * 64;

  const int s_row = tid >> 2;
  const int s_oct = tid & 3;
  const int g_row = m0 + s_row;
  const int g_rowc = (g_row < M) ? g_row : (M - 1);
  const unsigned short* ab = yb + (size_t)g_rowc * K + s_oct * 8;

  const int rgrp = wave & 1;
  const int ch = wave >> 1;
  const int coln = lane & 15;
  const int rown = (lane >> 4) * 4;
  const int colbase = ch * 64 + coln * 4;

  auto issueB = [&](const unsigned short* Bh, const unsigned short* Bl, int ks) {
    const unsigned short* sh = Bh + (size_t)ks * 4096 + wave * 1024;
    const unsigned short* sl = Bl + (size_t)ks * 4096 + wave * 1024;
    gl_lds16(sh + lane * 8, &Bhs[wave * 1024]);
    gl_lds16(sh + 512 + lane * 8, &Bhs[wave * 1024 + 512]);
    gl_lds16(sl + lane * 8, &Bls[wave * 1024]);
    gl_lds16(sl + 512 + lane * 8, &Bls[wave * 1024 + 512]);
  };

  f32x4 acc[2][4];
#pragma unroll
  for (int r = 0; r < 2; ++r)
#pragma unroll
    for (int c = 0; c < 4; ++c) acc[r][c] = (f32x4){0.f, 0.f, 0.f, 0.f};

  // ================= stage 1: h = relu(y @ W1 + b1) =================
  for (int ks = 0; ks < KSTEPS; ++ks) {
    *(uint4*)&Ah[s_row * ASTR + s_oct * 8] = *(const uint4*)(ab + ks * 32);
    issueB(B1h, B1l, ks);
    __syncthreads();
    bf16x8 a0 = *(const bf16x8*)&Ah[(rgrp * 32 + (lane & 15)) * ASTR + (lane >> 4) * 8];
    bf16x8 a1 = *(const bf16x8*)&Ah[(rgrp * 32 + 16 + (lane & 15)) * ASTR + (lane >> 4) * 8];
#pragma unroll
    for (int c = 0; c < 4; ++c) {
      int ct = ch * 4 + c;
      bf16x8 bh = *(const bf16x8*)&Bhs[(ct * 64 + lane) * 8];
      bf16x8 bl = *(const bf16x8*)&Bls[(ct * 64 + lane) * 8];
      acc[0][c] = __builtin_amdgcn_mfma_f32_16x16x32_bf16(a0, bh, acc[0][c], 0, 0, 0);
      acc[0][c] = __builtin_amdgcn_mfma_f32_16x16x32_bf16(a0, bl, acc[0][c], 0, 0, 0);
      acc[1][c] = __builtin_amdgcn_mfma_f32_16x16x32_bf16(a1, bh, acc[1][c], 0, 0, 0);
      acc[1][c] = __builtin_amdgcn_mfma_f32_16x16x32_bf16(a1, bl, acc[1][c], 0, 0, 0);
    }
    __syncthreads();
  }

  // ---- h -> LDS bf16: slot c holds hidden col colbase+c ----
  {
    const float4 bv = *(const float4*)(b1 + colbase);
#pragma unroll
    for (int r = 0; r < 2; ++r) {
#pragma unroll
      for (int reg = 0; reg < 4; ++reg) {
        int lrow = rgrp * 32 + r * 16 + rown + reg;
        ushort4 hb;
        hb.x = f2bf(fmaxf(acc[r][0][reg] + bv.x, 0.f));
        hb.y = f2bf(fmaxf(acc[r][1][reg] + bv.y, 0.f));
        hb.z = f2bf(fmaxf(acc[r][2][reg] + bv.z, 0.f));
        hb.w = f2bf(fmaxf(acc[r][3][reg] + bv.w, 0.f));
        *(ushort4*)&Hb[lrow * HSTR + colbase] = hb;
      }
    }
#pragma unroll
    for (int r = 0; r < 2; ++r)
#pragma unroll
      for (int c = 0; c < 4; ++c) acc[r][c] = (f32x4){0.f, 0.f, 0.f, 0.f};
  }

  // ================= stage 2: X = h @ W2 + b2 =================
  for (int ks = 0; ks < KSTEPS; ++ks) {
    issueB(B2h, B2l, ks);
    __syncthreads();  // first iter: also publishes Hb to all waves
    bf16x8 a0 = *(const bf16x8*)&Hb[(rgrp * 32 + (lane & 15)) * HSTR + ks * 32 + (lane >> 4) * 8];
    bf16x8 a1 = *(const bf16x8*)&Hb[(rgrp * 32 + 16 + (lane & 15)) * HSTR + ks * 32 + (lane >> 4) * 8];
#pragma unroll
    for (int c = 0; c < 4; ++c) {
      int ct = ch * 4 + c;
      bf16x8 bh = *(const bf16x8*)&Bhs[(ct * 64 + lane) * 8];
      bf16x8 bl = *(const bf16x8*)&Bls[(ct * 64 + lane) * 8];
      acc[0][c] = __builtin_amdgcn_mfma_f32_16x16x32_bf16(a0, bh, acc[0][c], 0, 0, 0);
      acc[0][c] = __builtin_amdgcn_mfma_f32_16x16x32_bf16(a0, bl, acc[0][c], 0, 0, 0);
      acc[1][c] = __builtin_amdgcn_mfma_f32_16x16x32_bf16(a1, bh, acc[1][c], 0, 0, 0);
      acc[1][c] = __builtin_amdgcn_mfma_f32_16x16x32_bf16(a1, bl, acc[1][c], 0, 0, 0);
    }
    __syncthreads();  // last iter: Hb reads complete -> safe to reuse below
  }

  const float4 bv = *(const float4*)(b2 + colbase);

  if (tw == nullptr) {
    // ---- layer-1 epilogue: bf16 mirror only ----
#pragma unroll
    for (int r = 0; r < 2; ++r) {
#pragma unroll
      for (int reg = 0; reg < 4; ++reg) {
        int row = m0 + rgrp * 32 + r * 16 + rown + reg;
        if (row < M) {
          ushort4 hb;
          hb.x = f2bf(acc[r][0][reg] + bv.x);
          hb.y = f2bf(acc[r][1][reg] + bv.y);
          hb.z = f2bf(acc[r][2][reg] + bv.z);
          hb.w = f2bf(acc[r][3][reg] + bv.w);
          *(ushort4*)&xb_out[(size_t)row * DH + colbase] = hb;
        }
      }
    }
  } else {
    // ---- layer-2 fused-tail epilogue: z + BN partials, no feature write ----
    float* zpart = (float*)Hb;  // 64 x 33 fp32 = 8.4 KB (fits in 17.4 KB)
    const float4 tw4 = *(const float4*)(tw + colbase);
#pragma unroll
    for (int r = 0; r < 2; ++r) {
#pragma unroll
      for (int reg = 0; reg < 4; ++reg) {
        int lrow = rgrp * 32 + r * 16 + rown + reg;
        float4 v;
        v.x = acc[r][0][reg] + bv.x;
        v.y = acc[r][1][reg] + bv.y;
        v.z = acc[r][2][reg] + bv.z;
        v.w = acc[r][3][reg] + bv.w;
        zpart[lrow * 33 + ch * 16 + coln] =
            v.x * tw4.x + v.y * tw4.y + v.z * tw4.z + v.w * tw4.w;
      }
    }
    __syncthreads();
    if (tid < 64) {
      int row = m0 + tid;
      float s = 0.f;
#pragma unroll
      for (int k = 0; k < 32; ++k) s += zpart[tid * 33 + k];
      float zv = s + tb[0];
      bool valid = row < M;
      if (valid) z[row] = zv;
      float a = valid ? zv : 0.f;
      float q = valid ? zv * zv : 0.f;
#pragma unroll
      for (int m = 32; m; m >>= 1) {
        a += __shfl_xor(a, m);
        q += __shfl_xor(q, m);
      }
      if (tid == 0) {
        atomicAdd(&red[0], a);
        atomicAdd(&red[1], q);
      }
    }
  }
}

// ---------------------------------------------------------------------------
// CSR build: exclusive scan over PADDED degrees (pad to multiple of 4 so the
// aggregate's index loads are aligned int4 and its edge loop has no tails).
// Pad slots point at dummy node N_NODES whose xb row is zeroed.
// ---------------------------------------------------------------------------
__global__ __launch_bounds__(256) void scan_block(const int* __restrict__ cnt,
                                                  int* __restrict__ rs,
                                                  int* __restrict__ partials) {
  int t = threadIdx.x;
  int i = blockIdx.x * 256 + t;
  int v = (i < N_NODES) ? ((cnt[i] + 3) & ~3) : 0;   // padded degree
  __shared__ int s[256];
  s[t] = v;
  __syncthreads();
#pragma unroll
  for (int off = 1; off < 256; off <<= 1) {
    int add = (t >= off) ? s[t - off] : 0;
    __syncthreads();
    s[t] += add;
    __syncthreads();
  }
  if (i < N_NODES) rs[i] = s[t] - v;
  if (t == 255) partials[blockIdx.x] = s[255];
}

__global__ __launch_bounds__(256) void scan_partials(int* __restrict__ partials,
                                                     float* __restrict__ red) {
  int t = threadIdx.x;
  if (t == 0) { red[0] = 0.f; red[1] = 0.f; }   // BN partial reset (free ride)
  int v = (t < SCAN_BLOCKS) ? partials[t] : 0;
  __shared__ int s[256];
  s[t] = v;
  __syncthreads();
#pragma unroll
  for (int off = 1; off < 256; off <<= 1) {
    int add = (t >= off) ? s[t - off] : 0;
    __syncthreads();
    s[t] += add;
    __syncthreads();
  }
  if (t < SCAN_BLOCKS) partials[t] = s[t] - v;
}

// add block offsets + write pad slots + zero cnt (cursor) — merged launch.
// Pad bounds derive locally: rs[i+1] = v + padded(cnt[i]).
__global__ __launch_bounds__(256) void add_offsets_pad(
    int* __restrict__ rs, const int* __restrict__ partials,
    int* __restrict__ cnt, int* __restrict__ esrc) {
  int i = blockIdx.x * 256 + threadIdx.x;
  if (i >= N_NODES) return;
  int v = rs[i] + partials[blockIdx.x];
  rs[i] = v;
  int d = cnt[i];
  cnt[i] = 0;
  int pe = v + ((d + 3) & ~3);
  if (i == N_NODES - 1) rs[N_NODES] = pe;
  for (int k = v + d; k < pe; ++k) esrc[k] = N_NODES;
}

// ---------------------------------------------------------------------------
// Aggregation gather (all-bf16): yb[i] = bf16(xb[i] + sum_j xb[src_j]).
// Wave per node; lane handles dims (2*lane, 2*lane+1) via one uint load/edge.
// Self-term from xb (bf16) — R10: fp32 X dropped pipeline-wide.
// Edge lists padded to x4 with the zero-row dummy: aligned int4 index loads.
// ---------------------------------------------------------------------------
__global__ __launch_bounds__(256) void gin_aggregate_bf16(
    const unsigned short* __restrict__ xb,
    const int* __restrict__ rs, const int* __restrict__ esrc,
    unsigned* __restrict__ yb) {
  int node = blockIdx.x * 4 + (threadIdx.x >> 6);
  int lane = threadIdx.x & 63;
  if (node >= N_NODES) return;
  const unsigned* xb2 = (const unsigned*)xb;  // 2 bf16 per uint
  unsigned vs = xb2[(size_t)node * 64 + lane];
  float2 acc;
  acc.x = __uint_as_float(vs << 16);
  acc.y = __uint_as_float(vs & 0xFFFF0000u);
  int beg = rs[node];
  int end = rs[node + 1];
  int j = beg;
  for (; j + 8 <= end; j += 8) {
    int4 ia = *(const int4*)&esrc[j];
    int4 ib = *(const int4*)&esrc[j + 4];
    unsigned v0 = xb2[(size_t)ia.x * 64 + lane];
    unsigned v1 = xb2[(size_t)ia.y * 64 + lane];
    unsigned v2 = xb2[(size_t)ia.z * 64 + lane];
    unsigned v3 = xb2[(size_t)ia.w * 64 + lane];
    unsigned v4 = xb2[(size_t)ib.x * 64 + lane];
    unsigned v5 = xb2[(size_t)ib.y * 64 + lane];
    unsigned v6 = xb2[(size_t)ib.z * 64 + lane];
    unsigned v7 = xb2[(size_t)ib.w * 64 + lane];
    acc.x += ((__uint_as_float(v0 << 16) + __uint_as_float(v1 << 16)) +
              (__uint_as_float(v2 << 16) + __uint_as_float(v3 << 16))) +
             ((__uint_as_float(v4 << 16) + __uint_as_float(v5 << 16)) +
              (__uint_as_float(v6 << 16) + __uint_as_float(v7 << 16)));
    acc.y += ((__uint_as_float(v0 & 0xFFFF0000u) + __uint_as_float(v1 & 0xFFFF0000u)) +
              (__uint_as_float(v2 & 0xFFFF0000u) + __uint_as_float(v3 & 0xFFFF0000u))) +
             ((__uint_as_float(v4 & 0xFFFF0000u) + __uint_as_float(v5 & 0xFFFF0000u)) +
              (__uint_as_float(v6 & 0xFFFF0000u) + __uint_as_float(v7 & 0xFFFF0000u)));
  }
  if (j < end) {  // exactly one aligned 4-batch remains
    int4 ia = *(const int4*)&esrc[j];
    unsigned v0 = xb2[(size_t)ia.x * 64 + lane];
    unsigned v1 = xb2[(size_t)ia.y * 64 + lane];
    unsigned v2 = xb2[(size_t)ia.z * 64 + lane];
    unsigned v3 = xb2[(size_t)ia.w * 64 + lane];
    acc.x += (__uint_as_float(v0 << 16) + __uint_as_float(v1 << 16)) +
             (__uint_as_float(v2 << 16) + __uint_as_float(v3 << 16));
    acc.y += (__uint_as_float(v0 & 0xFFFF0000u) + __uint_as_float(v1 & 0xFFFF0000u)) +
             (__uint_as_float(v2 & 0xFFFF0000u) + __uint_as_float(v3 & 0xFFFF0000u));
  }
  yb[(size_t)node * 64 + lane] =
      (unsigned)f2bf(acc.x) | ((unsigned)f2bf(acc.y) << 16);
}

// ---------------------------------------------------------------------------
// BN apply: out = (z - mu) * rsqrt(var + eps) * gamma + beta.
// ---------------------------------------------------------------------------
__global__ __launch_bounds__(256) void bn2(const float* __restrict__ z,
                                           const float* __restrict__ red,
                                           const float* __restrict__ gamma,
                                           const float* __restrict__ beta,
                                           float* __restrict__ out) {
  int i = blockIdx.x * 256 + threadIdx.x;
  if (i >= N_NODES) return;
  float mu = red[0] * (1.0f / N_NODES);
  float var = red[1] * (1.0f / N_NODES) - mu * mu;
  out[i] = (z[i] - mu) * rsqrtf(var + BN_EPS) * gamma[0] + beta[0];
}

// ---------------------------------------------------------------------------
extern "C" void kernel_launch(void* const* d_in, const int* in_sizes, int n_in,
                              void* d_out, int out_size, void* d_ws, size_t ws_size,
                              hipStream_t stream) {
  const float* feature = (const float*)d_in[0];
  const int* eidx = (const int*)d_in[1];
  const float* head_W = (const float*)d_in[2];
  const float* head_b = (const float*)d_in[3];
  const float* gin_W1 = (const float*)d_in[4];
  const float* gin_b1 = (const float*)d_in[5];
  const float* lin_W1 = (const float*)d_in[6];
  const float* lin_b1 = (const float*)d_in[7];
  const float* gin_W2 = (const float*)d_in[8];
  const float* gin_b2 = (const float*)d_in[9];
  const float* lin_W2 = (const float*)d_in[10];
  const float* lin_b2 = (const float*)d_in[11];
  const float* tail_W = (const float*)d_in[12];
  const float* tail_b = (const float*)d_in[13];
  const float* bn_gamma = (const float*)d_in[14];
  const float* bn_beta = (const float*)d_in[15];

  float* z = (float*)d_ws;                       // N
  float* red = z + N_NODES;                      // 2 floats
  int* row_start = (int*)(red + 2);              // N+1
  int* cnt = row_start + (N_NODES + 1);          // N
  int* partials = cnt + N_NODES;                 // 256
  int* esrc = (int*)(((uintptr_t)(partials + 256) + 15) & ~(uintptr_t)15);
  // padded CSR: at most E + 3*N = 750000 slots
  unsigned short* wp =
      (unsigned short*)(((uintptr_t)(esrc + 760000) + 15) & ~(uintptr_t)15);
  unsigned short* hH = wp;            // head hi: 512*128
  unsigned short* hL = hH + 65536;    // head lo
  unsigned short* g1H = hL + 65536;   // 128*128 each below
  unsigned short* g1L = g1H + 16384;
  unsigned short* l1H = g1L + 16384;
  unsigned short* l1L = l1H + 16384;
  unsigned short* g2H = l1L + 16384;
  unsigned short* g2L = g2H + 16384;
  unsigned short* l2H = g2L + 16384;
  unsigned short* l2L = l2H + 16384;
  unsigned short* xb = l2L + 16384;              // bf16 features, (N+1) x 128
  unsigned short* yb = xb + (size_t)(N_NODES + 1) * DH;  // agg out bf16, N x 128

  const int gin_grid = (N_NODES + 63) / 64;      // 782 (BM=64)
  const int edge_grid = (N_EDGES + 255) / 256;   // 2344
  const int agg_grid = (N_NODES + 3) / 4;

  // ---- zero degree counters ----
  hipMemsetAsync(cnt, 0, N_NODES * sizeof(int), stream);

  // ---- weight pre-split + degree count + xb dummy zero: one launch ----
  convert_W5_count<<<512 + edge_grid, 256, 0, stream>>>(
      head_W, gin_W1, lin_W1, gin_W2, lin_W2, hH, hL, g1H, g1L, l1H, l1L,
      g2H, g2L, l2H, l2L, eidx, cnt,
      (unsigned*)(xb + (size_t)N_NODES * DH));

  // ---- CSR build over padded degrees ----
  scan_block<<<SCAN_BLOCKS, 256, 0, stream>>>(cnt, row_start, partials);
  scan_partials<<<1, 256, 0, stream>>>(partials, red);   // also zeroes red
  add_offsets_pad<<<SCAN_BLOCKS, 256, 0, stream>>>(row_start, partials, cnt, esrc);

  // ---- head GEMM (fused with fill_csr; bf16 mirror only) ----
  gemm_head_fill<<<HEAD_GRID + edge_grid, 256, 0, stream>>>(
      feature, hH, hL, head_b, xb, N_NODES, eidx, row_start, cnt, esrc);

  // ---- layer 1 (aggregate -> fused GIN MLP pair; emits next bf16 mirror) ----
  gin_aggregate_bf16<<<agg_grid, 256, 0, stream>>>(xb, row_start, esrc,
                                                   (unsigned*)yb);
  gemm_gin<<<gin_grid, 256, 0, stream>>>(yb, g1H, g1L, gin_b1, l1H, l1L,
                                         lin_b1, xb, N_NODES,
                                         nullptr, nullptr, nullptr, nullptr);

  // ---- layer 2 (aggregate -> fused tail: z + BN partials) ----
  gin_aggregate_bf16<<<agg_grid, 256, 0, stream>>>(xb, row_start, esrc,
                                                   (unsigned*)yb);
  gemm_gin<<<gin_grid, 256, 0, stream>>>(yb, g2H, g2L, gin_b2, l2H, l2L,
                                         lin_b2, nullptr, N_NODES,
                                         tail_W, tail_b, z, red);

  // ---- batchnorm apply ----
  bn2<<<(N_NODES + 255) / 256, 256, 0, stream>>>(z, red, bn_gamma, bn_beta, (float*)d_out);
}

// Round 11
// 353.757 us; speedup vs baseline: 1.1675x; 1.0298x over previous
//
#include <hip/hip_runtime.h>

#define N_NODES 50000
#define N_EDGES 600000
#define DH 128
#define BN_EPS 1e-5f
#define SCAN_BLOCKS ((N_NODES + 255) / 256)   // 196
#define HEAD_GRID ((N_NODES + 63) / 64)       // 782

typedef __attribute__((ext_vector_type(8))) short bf16x8;
typedef __attribute__((ext_vector_type(4))) float f32x4;

// round-to-nearest-even fp32 -> bf16 (bit trick, sign-safe)
__device__ inline unsigned short f2bf(float x) {
  unsigned u = __float_as_uint(x);
  return (unsigned short)((u + 0x7FFFu + ((u >> 16) & 1u)) >> 16);
}
__device__ inline float bf2f(unsigned short h) {
  return __uint_as_float(((unsigned)h) << 16);
}

// async global->LDS, 16 B per lane: lane i's data lands at lds_base + i*16.
__device__ inline void gl_lds16(const unsigned short* g, unsigned short* l) {
  __builtin_amdgcn_global_load_lds(
      (const __attribute__((address_space(1))) unsigned int*)g,
      (__attribute__((address_space(3))) unsigned int*)l, 16, 0, 0);
}

// ---------------------------------------------------------------------------
// Fused weight pre-split + edge-degree count (block-range fusion) + dummy-row
// zero for BOTH feature ping-pong buffers (block 0 rides along).
// Column-slot permutation: output col n placed so the epilogue lane's 4
// c-values are CONTIGUOUS output columns (colbase = ch*64 + coln*4 + c):
//   slot ct = (n>>6)*4 + (n&3), slot coln = (n>>2)&15
// k-mapping: plane[((kstep32*8 + ctile)*64 + lane)*8 + j],
// k = kstep32*32 + (lane>>4)*8 + j. W split hi/lo (Wh+Wl == W to 2^-17).
// ---------------------------------------------------------------------------
__global__ __launch_bounds__(256) void convert_W5_count(
    const float* __restrict__ hW, const float* __restrict__ g1,
    const float* __restrict__ l1, const float* __restrict__ g2,
    const float* __restrict__ l2,
    unsigned short* __restrict__ hH, unsigned short* __restrict__ hL,
    unsigned short* __restrict__ g1H, unsigned short* __restrict__ g1L,
    unsigned short* __restrict__ l1H, unsigned short* __restrict__ l1L,
    unsigned short* __restrict__ g2H, unsigned short* __restrict__ g2L,
    unsigned short* __restrict__ l2H, unsigned short* __restrict__ l2L,
    const int* __restrict__ eidx, int* __restrict__ cnt,
    unsigned* __restrict__ dummy0, unsigned* __restrict__ dummy1) {
  int b = blockIdx.x;
  if (b >= 512) {
    int e = (b - 512) * 256 + threadIdx.x;
    if (e < N_EDGES) atomicAdd(&cnt[eidx[N_EDGES + e]], 1);
    return;
  }
  if (b == 0 && threadIdx.x < 64) {
    dummy0[threadIdx.x] = 0u;   // 128 bf16 zeros each
    dummy1[threadIdx.x] = 0u;
  }
  const float* W;
  unsigned short *hi, *lo;
  int idx;
  if (b < 256) {
    W = hW; hi = hH; lo = hL;
    idx = b * 256 + threadIdx.x;
  } else {
    int w = (b - 256) >> 6;
    idx = ((b - 256) & 63) * 256 + threadIdx.x;
    W = (w == 0) ? g1 : (w == 1) ? l1 : (w == 2) ? g2 : l2;
    hi = (w == 0) ? g1H : (w == 1) ? l1H : (w == 2) ? g2H : l2H;
    lo = (w == 0) ? g1L : (w == 1) ? l1L : (w == 2) ? g2L : l2L;
  }
  int k = idx >> 7;
  int n = idx & 127;
  float x = W[idx];
  unsigned short h = f2bf(x);
  unsigned short l = f2bf(x - bf2f(h));
  int kstep = k >> 5;
  int ctile = ((n >> 6) << 2) | (n & 3);
  int cs = (n >> 2) & 15;
  int lane = ((k >> 3) & 3) * 16 + cs;
  int j = k & 7;
  size_t off = ((size_t)(kstep * 8 + ctile) * 64 + lane) * 8 + j;
  hi[off] = h;
  lo[off] = l;
}

// ---------------------------------------------------------------------------
// Head GEMM (K=512) — proven form + fused fill_csr; bf16-only output (fp32 X
// dropped pipeline-wide, R10). BM=64, BK=64, 2 barriers/kstep. LDS ~41 KB.
// ---------------------------------------------------------------------------
__global__ __launch_bounds__(256) void gemm_head_fill(
    const float* __restrict__ A,
    const unsigned short* __restrict__ Bh, const unsigned short* __restrict__ Bl,
    const float* __restrict__ bias,
    unsigned short* __restrict__ xb_out, int M,
    const int* __restrict__ eidx, const int* __restrict__ rs,
    int* __restrict__ cursor, int* __restrict__ esrc) {
  constexpr int K = 512;
  constexpr int KSTEPS = K / 64;
  constexpr int ASTR = 72;  // 64 k + 8 pad (2-way bank alias = free)
  __shared__ __align__(16) unsigned short Ah[64 * ASTR];   // 9.2 KB
  __shared__ __align__(16) unsigned short Bhs[2][4096];    // 16 KB
  __shared__ __align__(16) unsigned short Bls[2][4096];    // 16 KB

  if (blockIdx.x >= HEAD_GRID) {
    // ---- fill_csr part: scatter edge sources into CSR slots ----
    int e = (blockIdx.x - HEAD_GRID) * 256 + threadIdx.x;
    if (e < N_EDGES) {
      int d = eidx[N_EDGES + e];
      int p = atomicAdd(&cursor[d], 1);
      esrc[rs[d] + p] = eidx[e];
    }
    return;
  }

  const int tid = threadIdx.x;
  const int wave = tid >> 6;
  const int lane = tid & 63;
  const int m0 = blockIdx.x * 64;

  // A staging: thread owns row tid>>2 (0..63), 16-elem group tid&3
  const int s_row = tid >> 2;
  const int s_grp = tid & 3;
  const int g_row = m0 + s_row;
  const int g_rowc = (g_row < M) ? g_row : (M - 1);
  const float* af = A + (size_t)g_rowc * K + s_grp * 16;

  const int rgrp = wave & 1;  // 32-row group
  const int ch = wave >> 1;   // 64-col half

  f32x4 acc[2][4];
#pragma unroll
  for (int r = 0; r < 2; ++r)
#pragma unroll
    for (int c = 0; c < 4; ++c) acc[r][c] = (f32x4){0.f, 0.f, 0.f, 0.f};

  for (int ks = 0; ks < KSTEPS; ++ks) {
    // ---- stage A (64 rows x 64 k fp32 -> bf16) ----
    {
      float4 f0 = *(const float4*)(af + ks * 64);
      float4 f1 = *(const float4*)(af + ks * 64 + 4);
      float4 f2 = *(const float4*)(af + ks * 64 + 8);
      float4 f3 = *(const float4*)(af + ks * 64 + 12);
      ushort4 h0, h1, h2, h3;
      h0.x = f2bf(f0.x); h0.y = f2bf(f0.y); h0.z = f2bf(f0.z); h0.w = f2bf(f0.w);
      h1.x = f2bf(f1.x); h1.y = f2bf(f1.y); h1.z = f2bf(f1.z); h1.w = f2bf(f1.w);
      h2.x = f2bf(f2.x); h2.y = f2bf(f2.y); h2.z = f2bf(f2.z); h2.w = f2bf(f2.w);
      h3.x = f2bf(f3.x); h3.y = f2bf(f3.y); h3.z = f2bf(f3.z); h3.w = f2bf(f3.w);
      int base = s_row * ASTR + s_grp * 16;
      *(ushort4*)&Ah[base + 0] = h0;
      *(ushort4*)&Ah[base + 4] = h1;
      *(ushort4*)&Ah[base + 8] = h2;
      *(ushort4*)&Ah[base + 12] = h3;
    }
    // ---- stage B: two 32-k sub-steps, 8 KB per plane each ----
#pragma unroll
    for (int s = 0; s < 2; ++s) {
      const unsigned short* sh = Bh + (size_t)(2 * ks + s) * 4096 + wave * 1024;
      const unsigned short* sl = Bl + (size_t)(2 * ks + s) * 4096 + wave * 1024;
      gl_lds16(sh + lane * 8, &Bhs[s][wave * 1024]);
      gl_lds16(sh + 512 + lane * 8, &Bhs[s][wave * 1024 + 512]);
      gl_lds16(sl + lane * 8, &Bls[s][wave * 1024]);
      gl_lds16(sl + 512 + lane * 8, &Bls[s][wave * 1024 + 512]);
    }
    __syncthreads();

    // ---- compute: 2 k-chunks x 4 c-tiles x (hi+lo) x 2 row-frags ----
#pragma unroll
    for (int s = 0; s < 2; ++s) {
      bf16x8 a0 = *(const bf16x8*)&Ah[(rgrp * 32 + (lane & 15)) * ASTR + s * 32 + (lane >> 4) * 8];
      bf16x8 a1 = *(const bf16x8*)&Ah[(rgrp * 32 + 16 + (lane & 15)) * ASTR + s * 32 + (lane >> 4) * 8];
#pragma unroll
      for (int c = 0; c < 4; ++c) {
        int ct = ch * 4 + c;
        bf16x8 bh = *(const bf16x8*)&Bhs[s][(ct * 64 + lane) * 8];
        bf16x8 bl = *(const bf16x8*)&Bls[s][(ct * 64 + lane) * 8];
        acc[0][c] = __builtin_amdgcn_mfma_f32_16x16x32_bf16(a0, bh, acc[0][c], 0, 0, 0);
        acc[0][c] = __builtin_amdgcn_mfma_f32_16x16x32_bf16(a0, bl, acc[0][c], 0, 0, 0);
        acc[1][c] = __builtin_amdgcn_mfma_f32_16x16x32_bf16(a1, bh, acc[1][c], 0, 0, 0);
        acc[1][c] = __builtin_amdgcn_mfma_f32_16x16x32_bf16(a1, bl, acc[1][c], 0, 0, 0);
      }
    }
    __syncthreads();
  }

  // ---- epilogue: bf16 mirror only (slot c = output col colbase+c) ----
  const int coln = lane & 15;
  const int rown = (lane >> 4) * 4;
  const int colbase = ch * 64 + coln * 4;
  const float4 bv = *(const float4*)(bias + colbase);
#pragma unroll
  for (int r = 0; r < 2; ++r) {
#pragma unroll
    for (int reg = 0; reg < 4; ++reg) {
      int row = m0 + rgrp * 32 + r * 16 + rown + reg;
      if (row < M) {
        ushort4 hb;
        hb.x = f2bf(fmaxf(acc[r][0][reg] + bv.x, 0.f));
        hb.y = f2bf(fmaxf(acc[r][1][reg] + bv.y, 0.f));
        hb.z = f2bf(fmaxf(acc[r][2][reg] + bv.z, 0.f));
        hb.w = f2bf(fmaxf(acc[r][3][reg] + bv.w, 0.f));
        *(ushort4*)&xb_out[(size_t)row * DH + colbase] = hb;
      }
    }
  }
}

// ---------------------------------------------------------------------------
// FUSED aggregate + GIN MLP pair (R11). The agg->gin dependency is
// block-local: gin block b consumes exactly y-rows 64b..64b+63, which depend
// only on the previous layer's xb (complete before launch). So each wave
// aggregates 16 of the block's nodes directly into Hb (same summation order
// as the old standalone kernel -> bit-identical y), and stage 1 reads its
// A-fragments straight from Hb. Deletes the aggregate launch, the yb array,
// and gin's per-kstep A-loads. B1(0) is prefetched before the gather so the
// first kstep's B-latency hides under it. Ping-pong feature buffers prevent
// the read/write race (xb_in != xb_out).
// Stage 2: h = relu(...) overwrites Hb (barrier-ordered as before).
// Epilogue: layer 1 -> xb_out bf16; layer 2 -> fused tail (z + BN partials).
// LDS: 8 + 8 + 17.4 = 33.4 KB -> 4 blocks/CU.
// ---------------------------------------------------------------------------
__global__ __launch_bounds__(256) void gemm_gin_fused(
    const unsigned short* __restrict__ xb_in,
    const int* __restrict__ rs, const int* __restrict__ esrc,
    const unsigned short* __restrict__ B1h, const unsigned short* __restrict__ B1l,
    const float* __restrict__ b1,
    const unsigned short* __restrict__ B2h, const unsigned short* __restrict__ B2l,
    const float* __restrict__ b2,
    unsigned short* __restrict__ xb_out, int M,
    const float* __restrict__ tw, const float* __restrict__ tb,
    float* __restrict__ z, float* __restrict__ red) {
  constexpr int KSTEPS = 4;   // K=128, BK=32
  constexpr int HSTR = 136;   // 128 + 8 pad
  __shared__ __align__(16) unsigned short Bhs[4096];       // 8 KB
  __shared__ __align__(16) unsigned short Bls[4096];       // 8 KB
  __shared__ __align__(16) unsigned short Hb[64 * HSTR];   // 17.4 KB (y, then h)

  const int tid = threadIdx.x;
  const int wave = tid >> 6;
  const int lane = tid & 63;
  const int m0 = blockIdx.x * 64;

  const int rgrp = wave & 1;
  const int ch = wave >> 1;
  const int coln = lane & 15;
  const int rown = (lane >> 4) * 4;
  const int colbase = ch * 64 + coln * 4;

  auto issueB = [&](const unsigned short* Bh, const unsigned short* Bl, int ks) {
    const unsigned short* sh = Bh + (size_t)ks * 4096 + wave * 1024;
    const unsigned short* sl = Bl + (size_t)ks * 4096 + wave * 1024;
    gl_lds16(sh + lane * 8, &Bhs[wave * 1024]);
    gl_lds16(sh + 512 + lane * 8, &Bhs[wave * 1024 + 512]);
    gl_lds16(sl + lane * 8, &Bls[wave * 1024]);
    gl_lds16(sl + 512 + lane * 8, &Bls[wave * 1024 + 512]);
  };

  // ---- B1(0) in flight before the gather phase ----
  issueB(B1h, B1l, 0);

  // ================= aggregation phase: y -> Hb (bf16) =================
  // Wave w aggregates local rows w*16..w*16+15; lane owns dims (2l, 2l+1).
  // Same edge-batch summation order as the old standalone kernel.
  {
    const unsigned* xb2 = (const unsigned*)xb_in;  // 2 bf16 per uint
    for (int i = 0; i < 16; ++i) {
      int lrow = wave * 16 + i;
      int node = m0 + lrow;
      float2 acc2 = {0.f, 0.f};
      if (node < M) {
        unsigned vs = xb2[(size_t)node * 64 + lane];
        acc2.x = __uint_as_float(vs << 16);
        acc2.y = __uint_as_float(vs & 0xFFFF0000u);
        int j = rs[node];
        int end = rs[node + 1];
        for (; j + 8 <= end; j += 8) {
          int4 ia = *(const int4*)&esrc[j];
          int4 ib = *(const int4*)&esrc[j + 4];
          unsigned v0 = xb2[(size_t)ia.x * 64 + lane];
          unsigned v1 = xb2[(size_t)ia.y * 64 + lane];
          unsigned v2 = xb2[(size_t)ia.z * 64 + lane];
          unsigned v3 = xb2[(size_t)ia.w * 64 + lane];
          unsigned v4 = xb2[(size_t)ib.x * 64 + lane];
          unsigned v5 = xb2[(size_t)ib.y * 64 + lane];
          unsigned v6 = xb2[(size_t)ib.z * 64 + lane];
          unsigned v7 = xb2[(size_t)ib.w * 64 + lane];
          acc2.x += ((__uint_as_float(v0 << 16) + __uint_as_float(v1 << 16)) +
                     (__uint_as_float(v2 << 16) + __uint_as_float(v3 << 16))) +
                    ((__uint_as_float(v4 << 16) + __uint_as_float(v5 << 16)) +
                     (__uint_as_float(v6 << 16) + __uint_as_float(v7 << 16)));
          acc2.y += ((__uint_as_float(v0 & 0xFFFF0000u) + __uint_as_float(v1 & 0xFFFF0000u)) +
                     (__uint_as_float(v2 & 0xFFFF0000u) + __uint_as_float(v3 & 0xFFFF0000u))) +
                    ((__uint_as_float(v4 & 0xFFFF0000u) + __uint_as_float(v5 & 0xFFFF0000u)) +
                     (__uint_as_float(v6 & 0xFFFF0000u) + __uint_as_float(v7 & 0xFFFF0000u)));
        }
        if (j < end) {  // exactly one aligned 4-batch remains
          int4 ia = *(const int4*)&esrc[j];
          unsigned v0 = xb2[(size_t)ia.x * 64 + lane];
          unsigned v1 = xb2[(size_t)ia.y * 64 + lane];
          unsigned v2 = xb2[(size_t)ia.z * 64 + lane];
          unsigned v3 = xb2[(size_t)ia.w * 64 + lane];
          acc2.x += (__uint_as_float(v0 << 16) + __uint_as_float(v1 << 16)) +
                    (__uint_as_float(v2 << 16) + __uint_as_float(v3 << 16));
          acc2.y += (__uint_as_float(v0 & 0xFFFF0000u) + __uint_as_float(v1 & 0xFFFF0000u)) +
                    (__uint_as_float(v2 & 0xFFFF0000u) + __uint_as_float(v3 & 0xFFFF0000u));
        }
      }
      // lane l owns dims 2l,2l+1 -> 4-B aligned LDS write, 2-way bank alias
      *(unsigned*)&Hb[lrow * HSTR + 2 * lane] =
          (unsigned)f2bf(acc2.x) | ((unsigned)f2bf(acc2.y) << 16);
    }
  }

  f32x4 acc[2][4];
#pragma unroll
  for (int r = 0; r < 2; ++r)
#pragma unroll
    for (int c = 0; c < 4; ++c) acc[r][c] = (f32x4){0.f, 0.f, 0.f, 0.f};

  // ================= stage 1: h = relu(y @ W1 + b1) =================
  for (int ks = 0; ks < KSTEPS; ++ks) {
    if (ks > 0) issueB(B1h, B1l, ks);
    __syncthreads();  // iter 0: publishes Hb (y) + B1(0)
    bf16x8 a0 = *(const bf16x8*)&Hb[(rgrp * 32 + (lane & 15)) * HSTR + ks * 32 + (lane >> 4) * 8];
    bf16x8 a1 = *(const bf16x8*)&Hb[(rgrp * 32 + 16 + (lane & 15)) * HSTR + ks * 32 + (lane >> 4) * 8];
#pragma unroll
    for (int c = 0; c < 4; ++c) {
      int ct = ch * 4 + c;
      bf16x8 bh = *(const bf16x8*)&Bhs[(ct * 64 + lane) * 8];
      bf16x8 bl = *(const bf16x8*)&Bls[(ct * 64 + lane) * 8];
      acc[0][c] = __builtin_amdgcn_mfma_f32_16x16x32_bf16(a0, bh, acc[0][c], 0, 0, 0);
      acc[0][c] = __builtin_amdgcn_mfma_f32_16x16x32_bf16(a0, bl, acc[0][c], 0, 0, 0);
      acc[1][c] = __builtin_amdgcn_mfma_f32_16x16x32_bf16(a1, bh, acc[1][c], 0, 0, 0);
      acc[1][c] = __builtin_amdgcn_mfma_f32_16x16x32_bf16(a1, bl, acc[1][c], 0, 0, 0);
    }
    __syncthreads();
  }

  // ---- h -> Hb (overwrites y; all stage-1 reads completed at last barrier) ----
  {
    const float4 bv = *(const float4*)(b1 + colbase);
#pragma unroll
    for (int r = 0; r < 2; ++r) {
#pragma unroll
      for (int reg = 0; reg < 4; ++reg) {
        int lrow = rgrp * 32 + r * 16 + rown + reg;
        ushort4 hb;
        hb.x = f2bf(fmaxf(acc[r][0][reg] + bv.x, 0.f));
        hb.y = f2bf(fmaxf(acc[r][1][reg] + bv.y, 0.f));
        hb.z = f2bf(fmaxf(acc[r][2][reg] + bv.z, 0.f));
        hb.w = f2bf(fmaxf(acc[r][3][reg] + bv.w, 0.f));
        *(ushort4*)&Hb[lrow * HSTR + colbase] = hb;
      }
    }
#pragma unroll
    for (int r = 0; r < 2; ++r)
#pragma unroll
      for (int c = 0; c < 4; ++c) acc[r][c] = (f32x4){0.f, 0.f, 0.f, 0.f};
  }

  // ================= stage 2: out = h @ W2 + b2 =================
  for (int ks = 0; ks < KSTEPS; ++ks) {
    issueB(B2h, B2l, ks);
    __syncthreads();  // first iter: also publishes h to all waves
    bf16x8 a0 = *(const bf16x8*)&Hb[(rgrp * 32 + (lane & 15)) * HSTR + ks * 32 + (lane >> 4) * 8];
    bf16x8 a1 = *(const bf16x8*)&Hb[(rgrp * 32 + 16 + (lane & 15)) * HSTR + ks * 32 + (lane >> 4) * 8];
#pragma unroll
    for (int c = 0; c < 4; ++c) {
      int ct = ch * 4 + c;
      bf16x8 bh = *(const bf16x8*)&Bhs[(ct * 64 + lane) * 8];
      bf16x8 bl = *(const bf16x8*)&Bls[(ct * 64 + lane) * 8];
      acc[0][c] = __builtin_amdgcn_mfma_f32_16x16x32_bf16(a0, bh, acc[0][c], 0, 0, 0);
      acc[0][c] = __builtin_amdgcn_mfma_f32_16x16x32_bf16(a0, bl, acc[0][c], 0, 0, 0);
      acc[1][c] = __builtin_amdgcn_mfma_f32_16x16x32_bf16(a1, bh, acc[1][c], 0, 0, 0);
      acc[1][c] = __builtin_amdgcn_mfma_f32_16x16x32_bf16(a1, bl, acc[1][c], 0, 0, 0);
    }
    __syncthreads();  // last iter: Hb reads complete -> safe to reuse below
  }

  const float4 bv = *(const float4*)(b2 + colbase);

  if (tw == nullptr) {
    // ---- layer-1 epilogue: bf16 features only ----
#pragma unroll
    for (int r = 0; r < 2; ++r) {
#pragma unroll
      for (int reg = 0; reg < 4; ++reg) {
        int row = m0 + rgrp * 32 + r * 16 + rown + reg;
        if (row < M) {
          ushort4 hb;
          hb.x = f2bf(acc[r][0][reg] + bv.x);
          hb.y = f2bf(acc[r][1][reg] + bv.y);
          hb.z = f2bf(acc[r][2][reg] + bv.z);
          hb.w = f2bf(acc[r][3][reg] + bv.w);
          *(ushort4*)&xb_out[(size_t)row * DH + colbase] = hb;
        }
      }
    }
  } else {
    // ---- layer-2 fused-tail epilogue: z + BN partials, no feature write ----
    float* zpart = (float*)Hb;  // 64 x 33 fp32 = 8.4 KB (fits in 17.4 KB)
    const float4 tw4 = *(const float4*)(tw + colbase);
#pragma unroll
    for (int r = 0; r < 2; ++r) {
#pragma unroll
      for (int reg = 0; reg < 4; ++reg) {
        int lrow = rgrp * 32 + r * 16 + rown + reg;
        float4 v;
        v.x = acc[r][0][reg] + bv.x;
        v.y = acc[r][1][reg] + bv.y;
        v.z = acc[r][2][reg] + bv.z;
        v.w = acc[r][3][reg] + bv.w;
        zpart[lrow * 33 + ch * 16 + coln] =
            v.x * tw4.x + v.y * tw4.y + v.z * tw4.z + v.w * tw4.w;
      }
    }
    __syncthreads();
    if (tid < 64) {
      int row = m0 + tid;
      float s = 0.f;
#pragma unroll
      for (int k = 0; k < 32; ++k) s += zpart[tid * 33 + k];
      float zv = s + tb[0];
      bool valid = row < M;
      if (valid) z[row] = zv;
      float a = valid ? zv : 0.f;
      float q = valid ? zv * zv : 0.f;
#pragma unroll
      for (int m = 32; m; m >>= 1) {
        a += __shfl_xor(a, m);
        q += __shfl_xor(q, m);
      }
      if (tid == 0) {
        atomicAdd(&red[0], a);
        atomicAdd(&red[1], q);
      }
    }
  }
}

// ---------------------------------------------------------------------------
// CSR build: exclusive scan over PADDED degrees (pad to multiple of 4 so the
// gather's index loads are aligned int4 and the edge loop has no tails).
// Pad slots point at dummy node N_NODES whose feature rows are zeroed.
// ---------------------------------------------------------------------------
__global__ __launch_bounds__(256) void scan_block(const int* __restrict__ cnt,
                                                  int* __restrict__ rs,
                                                  int* __restrict__ partials) {
  int t = threadIdx.x;
  int i = blockIdx.x * 256 + t;
  int v = (i < N_NODES) ? ((cnt[i] + 3) & ~3) : 0;   // padded degree
  __shared__ int s[256];
  s[t] = v;
  __syncthreads();
#pragma unroll
  for (int off = 1; off < 256; off <<= 1) {
    int add = (t >= off) ? s[t - off] : 0;
    __syncthreads();
    s[t] += add;
    __syncthreads();
  }
  if (i < N_NODES) rs[i] = s[t] - v;
  if (t == 255) partials[blockIdx.x] = s[255];
}

__global__ __launch_bounds__(256) void scan_partials(int* __restrict__ partials,
                                                     float* __restrict__ red) {
  int t = threadIdx.x;
  if (t == 0) { red[0] = 0.f; red[1] = 0.f; }   // BN partial reset (free ride)
  int v = (t < SCAN_BLOCKS) ? partials[t] : 0;
  __shared__ int s[256];
  s[t] = v;
  __syncthreads();
#pragma unroll
  for (int off = 1; off < 256; off <<= 1) {
    int add = (t >= off) ? s[t - off] : 0;
    __syncthreads();
    s[t] += add;
    __syncthreads();
  }
  if (t < SCAN_BLOCKS) partials[t] = s[t] - v;
}

// add block offsets + write pad slots + zero cnt (cursor) — merged launch.
// Pad bounds derive locally: rs[i+1] = v + padded(cnt[i]).
__global__ __launch_bounds__(256) void add_offsets_pad(
    int* __restrict__ rs, const int* __restrict__ partials,
    int* __restrict__ cnt, int* __restrict__ esrc) {
  int i = blockIdx.x * 256 + threadIdx.x;
  if (i >= N_NODES) return;
  int v = rs[i] + partials[blockIdx.x];
  rs[i] = v;
  int d = cnt[i];
  cnt[i] = 0;
  int pe = v + ((d + 3) & ~3);
  if (i == N_NODES - 1) rs[N_NODES] = pe;
  for (int k = v + d; k < pe; ++k) esrc[k] = N_NODES;
}

// ---------------------------------------------------------------------------
// BN apply: out = (z - mu) * rsqrt(var + eps) * gamma + beta.
// ---------------------------------------------------------------------------
__global__ __launch_bounds__(256) void bn2(const float* __restrict__ z,
                                           const float* __restrict__ red,
                                           const float* __restrict__ gamma,
                                           const float* __restrict__ beta,
                                           float* __restrict__ out) {
  int i = blockIdx.x * 256 + threadIdx.x;
  if (i >= N_NODES) return;
  float mu = red[0] * (1.0f / N_NODES);
  float var = red[1] * (1.0f / N_NODES) - mu * mu;
  out[i] = (z[i] - mu) * rsqrtf(var + BN_EPS) * gamma[0] + beta[0];
}

// ---------------------------------------------------------------------------
extern "C" void kernel_launch(void* const* d_in, const int* in_sizes, int n_in,
                              void* d_out, int out_size, void* d_ws, size_t ws_size,
                              hipStream_t stream) {
  const float* feature = (const float*)d_in[0];
  const int* eidx = (const int*)d_in[1];
  const float* head_W = (const float*)d_in[2];
  const float* head_b = (const float*)d_in[3];
  const float* gin_W1 = (const float*)d_in[4];
  const float* gin_b1 = (const float*)d_in[5];
  const float* lin_W1 = (const float*)d_in[6];
  const float* lin_b1 = (const float*)d_in[7];
  const float* gin_W2 = (const float*)d_in[8];
  const float* gin_b2 = (const float*)d_in[9];
  const float* lin_W2 = (const float*)d_in[10];
  const float* lin_b2 = (const float*)d_in[11];
  const float* tail_W = (const float*)d_in[12];
  const float* tail_b = (const float*)d_in[13];
  const float* bn_gamma = (const float*)d_in[14];
  const float* bn_beta = (const float*)d_in[15];

  float* z = (float*)d_ws;                       // N
  float* red = z + N_NODES;                      // 2 floats
  int* row_start = (int*)(red + 2);              // N+1
  int* cnt = row_start + (N_NODES + 1);          // N
  int* partials = cnt + N_NODES;                 // 256
  int* esrc = (int*)(((uintptr_t)(partials + 256) + 15) & ~(uintptr_t)15);
  // padded CSR: at most E + 3*N = 750000 slots
  unsigned short* wp =
      (unsigned short*)(((uintptr_t)(esrc + 760000) + 15) & ~(uintptr_t)15);
  unsigned short* hH = wp;            // head hi: 512*128
  unsigned short* hL = hH + 65536;    // head lo
  unsigned short* g1H = hL + 65536;   // 128*128 each below
  unsigned short* g1L = g1H + 16384;
  unsigned short* l1H = g1L + 16384;
  unsigned short* l1L = l1H + 16384;
  unsigned short* g2H = l1L + 16384;
  unsigned short* g2L = g2H + 16384;
  unsigned short* l2H = g2L + 16384;
  unsigned short* l2L = l2H + 16384;
  unsigned short* xb0 = l2L + 16384;             // bf16 features A, (N+1) x 128
  unsigned short* xb1 = xb0 + (size_t)(N_NODES + 1) * DH;  // features B (ping-pong)

  const int gin_grid = (N_NODES + 63) / 64;      // 782 (BM=64)
  const int edge_grid = (N_EDGES + 255) / 256;   // 2344

  // ---- zero degree counters ----
  hipMemsetAsync(cnt, 0, N_NODES * sizeof(int), stream);

  // ---- weight pre-split + degree count + both dummy-row zeros: one launch ----
  convert_W5_count<<<512 + edge_grid, 256, 0, stream>>>(
      head_W, gin_W1, lin_W1, gin_W2, lin_W2, hH, hL, g1H, g1L, l1H, l1L,
      g2H, g2L, l2H, l2L, eidx, cnt,
      (unsigned*)(xb0 + (size_t)N_NODES * DH),
      (unsigned*)(xb1 + (size_t)N_NODES * DH));

  // ---- CSR build over padded degrees ----
  scan_block<<<SCAN_BLOCKS, 256, 0, stream>>>(cnt, row_start, partials);
  scan_partials<<<1, 256, 0, stream>>>(partials, red);   // also zeroes red
  add_offsets_pad<<<SCAN_BLOCKS, 256, 0, stream>>>(row_start, partials, cnt, esrc);

  // ---- head GEMM (fused with fill_csr; writes xb0) ----
  gemm_head_fill<<<HEAD_GRID + edge_grid, 256, 0, stream>>>(
      feature, hH, hL, head_b, xb0, N_NODES, eidx, row_start, cnt, esrc);

  // ---- layer 1: fused aggregate + GIN MLP pair (xb0 -> xb1) ----
  gemm_gin_fused<<<gin_grid, 256, 0, stream>>>(
      xb0, row_start, esrc, g1H, g1L, gin_b1, l1H, l1L, lin_b1,
      xb1, N_NODES, nullptr, nullptr, nullptr, nullptr);

  // ---- layer 2: fused aggregate + GIN MLP pair + tail (xb1 -> z, red) ----
  gemm_gin_fused<<<gin_grid, 256, 0, stream>>>(
      xb1, row_start, esrc, g2H, g2L, gin_b2, l2H, l2L, lin_b2,
      nullptr, N_NODES, tail_W, tail_b, z, red);

  // ---- batchnorm apply ----
  bn2<<<(N_NODES + 255) / 256, 256, 0, stream>>>(z, red, bn_gamma, bn_beta, (float*)d_out);
}